// Round 9
// baseline (32252.246 us; speedup 1.0000x reference)
//
#include <hip/hip_runtime.h>
#include <math.h>

// Seq2SeqGRU persistent kernel. B=256, T=512, H=512, OUT=10.
// 256 WGs x 384 threads. WG = (rowgroup rg = blockIdx&15, hid-part hp = blockIdx>>4).
// All cross-WG traffic is rg-internal. Round-robin dispatch puts all 16 WGs of a
// rg on one XCD (XCC_ID-gated at runtime). FAST path: data via PLAIN stores
// (write-through L1 -> shared XCD L2) and PLAIN loads after a compiler-encoded
// agent-ACQUIRE fence (L1 invalidate). Flags stay dual: plain (L2) + sc1 (MALL)
// so every poll has a guaranteed-progress leg -> cannot hang (r8 lesson).
// SLOW path (gate fail) = r7's proven all-sc1 scheme.

#define Hdim 512
#define Bsz  256
#define Tlen 512
#define OUTL 10

typedef _Float16 half8 __attribute__((ext_vector_type(8)));
typedef float    f32x4 __attribute__((ext_vector_type(4)));
typedef unsigned long long u64;

__device__ __forceinline__ f32x4 mfma16(half8 a, half8 b, f32x4 c) {
    return __builtin_amdgcn_mfma_f32_16x16x32_f16(a, b, c, 0, 0, 0);
}
__device__ __forceinline__ float sigf(float v) { return 1.0f / (1.0f + __expf(-v)); }
__device__ __forceinline__ half8 h8(u64 lo, u64 hi) {
    union { u64 u[2]; half8 h; } t; t.u[0] = lo; t.u[1] = hi; return t.h;
}

// ---- agent-scope relaxed prims (sc1; r5-r7 proven, cross-XCD safe) ----
__device__ __forceinline__ u64 a_ld8(const void* p) {
    return __hip_atomic_load((const u64*)p, __ATOMIC_RELAXED, __HIP_MEMORY_SCOPE_AGENT); }
__device__ __forceinline__ float a_ld4(const void* p) {
    return __hip_atomic_load((const float*)p, __ATOMIC_RELAXED, __HIP_MEMORY_SCOPE_AGENT); }
__device__ __forceinline__ int a_ldi(const int* p) {
    return __hip_atomic_load(p, __ATOMIC_RELAXED, __HIP_MEMORY_SCOPE_AGENT); }
__device__ __forceinline__ void a_st8(void* p, u64 v) {
    __hip_atomic_store((u64*)p, v, __ATOMIC_RELAXED, __HIP_MEMORY_SCOPE_AGENT); }
__device__ __forceinline__ void a_st4(void* p, float v) {
    __hip_atomic_store((float*)p, v, __ATOMIC_RELAXED, __HIP_MEMORY_SCOPE_AGENT); }
__device__ __forceinline__ void a_st2(void* p, unsigned short v) {
    __hip_atomic_store((unsigned short*)p, v, __ATOMIC_RELAXED, __HIP_MEMORY_SCOPE_AGENT); }
__device__ __forceinline__ void a_sti(int* p, int v) {
    __hip_atomic_store(p, v, __ATOMIC_RELAXED, __HIP_MEMORY_SCOPE_AGENT); }

// agent acquire fence: compiler-encoded (L1 invalidate + waitcnts).
__device__ __forceinline__ void acq() {
    __builtin_amdgcn_fence(__ATOMIC_ACQUIRE, "agent");
}

// ---- templated data accessors: FAST = plain (L2-local), SLOW = sc1 agent ----
template<bool FAST> __device__ __forceinline__ float gld4(const float* p) {
    if constexpr (FAST) return *p; else return a_ld4(p);
}
template<bool FAST> __device__ __forceinline__ void gst4(float* p, float v) {
    if constexpr (FAST) *p = v; else a_st4(p, v);
}
template<bool FAST> __device__ __forceinline__ void gst8(_Float16* p, u64 v) {
    if constexpr (FAST) *(u64*)p = v; else a_st8(p, v);
}
template<bool FAST> __device__ __forceinline__ void gsth(_Float16* p, float v) {
    if constexpr (FAST) *p = (_Float16)v;
    else a_st2(p, __builtin_bit_cast(unsigned short, (_Float16)v));
}
template<bool FAST> __device__ __forceinline__ half8 gld16h(const _Float16* p) {
    if constexpr (FAST) return *(const half8*)p;
    else return h8(a_ld8(p), a_ld8(p + 4));
}

// signal: drain stores (FAST: to local L2; SLOW: to fabric), then flag store(s).
template<bool FAST>
__device__ __forceinline__ void sigS(int* slot, int val) {
    asm volatile("s_waitcnt vmcnt(0)" ::: "memory");
    if ((threadIdx.x & 63) == 0) {
        if constexpr (FAST) *(volatile int*)slot = val;   // L2-visible leg
        a_sti(slot, val);                                 // MALL-visible leg (progress guarantee)
    }
}
// wait: FAST = fence+plain probes (L2) with periodic sc1 probe; SLOW = r7 poll.
template<bool FAST, int NS>
__device__ __forceinline__ void waitN(int* base, int target) {
    if (target <= 0) return;
    int* p = base + ((threadIdx.x & 63) % NS);
    while (true) {
        if constexpr (FAST) {
            bool ok = false;
            #pragma unroll 1
            for (int k = 0; k < 8; ++k) {
                acq();
                int v = *(volatile int*)p;
                if (__all(v >= target)) { ok = true; break; }
            }
            if (ok) break;
        }
        int v2 = a_ldi(p);                 // guaranteed-progress leg
        if (__all(v2 >= target)) break;
        __builtin_amdgcn_s_sleep(1);
    }
    asm volatile("" ::: "memory");
}

__device__ __forceinline__ half8 ld_cvt(const float* p) {
    float4 a = *(const float4*)p;
    float4 b = *(const float4*)(p + 4);
    half8 v;
    v[0]=(_Float16)a.x; v[1]=(_Float16)a.y; v[2]=(_Float16)a.z; v[3]=(_Float16)a.w;
    v[4]=(_Float16)b.x; v[5]=(_Float16)b.y; v[6]=(_Float16)b.z; v[7]=(_Float16)b.w;
    return v;
}

// Stage both contiguous 16KB rg blocks -> LDS (linear, tile-major layout).
template<bool FAST>
__device__ __forceinline__ void stage2(_Float16* ldsAB, const _Float16* sA,
                                       const _Float16* sB, int tid) {
    if constexpr (FAST) {
        #pragma unroll
        for (int u = 0; u < 3; ++u) {
            int c = tid + u * 384;
            if (c < 1024) {
                half8 vb = *(const half8*)(sB + c * 8);
                half8 va = *(const half8*)(sA + c * 8);
                *(half8*)&ldsAB[8192 + c * 8] = vb;
                *(half8*)&ldsAB[c * 8] = va;
            }
        }
    } else {
        u64 tvB[6], tvA[6];
        #pragma unroll
        for (int u = 0; u < 6; ++u) {
            int c = tid + u * 384;
            if (c < 2048) { tvB[u] = a_ld8(sB + c * 4); tvA[u] = a_ld8(sA + c * 4); }
        }
        #pragma unroll
        for (int u = 0; u < 6; ++u) {
            int c = tid + u * 384;
            if (c < 2048) {
                *(u64*)&ldsAB[8192 + c * 4] = tvB[u];
                *(u64*)&ldsAB[c * 4] = tvA[u];
            }
        }
    }
}

// LayerNorm of 16 rows (one wave). hT f32 in/out; dst16rg tile-major f16 copy.
template<bool FAST>
__device__ void ln_rows(float* hT, _Float16* dst16rg, const float* gam, const float* bet,
                        int row0, int lane) {
    #pragma unroll 1
    for (int r = 0; r < 16; ++r) {
        float* pr_ = hT + (size_t)(row0 + r) * Hdim;
        float v[8];
        if constexpr (FAST) {
            float4 v0 = *(const float4*)(pr_ + lane * 8);
            float4 v1 = *(const float4*)(pr_ + lane * 8 + 4);
            v[0]=v0.x; v[1]=v0.y; v[2]=v0.z; v[3]=v0.w;
            v[4]=v1.x; v[5]=v1.y; v[6]=v1.z; v[7]=v1.w;
        } else {
            #pragma unroll
            for (int e = 0; e < 4; ++e) {
                union { u64 u; float f[2]; } c;
                c.u = a_ld8(pr_ + lane * 8 + e * 2);
                v[2*e] = c.f[0]; v[2*e+1] = c.f[1];
            }
        }
        float s = 0.f, sq = 0.f;
        #pragma unroll
        for (int e = 0; e < 8; ++e) { s += v[e]; sq += v[e] * v[e]; }
        #pragma unroll
        for (int m = 1; m < 64; m <<= 1) { s += __shfl_xor(s, m); sq += __shfl_xor(sq, m); }
        float mean = s * (1.0f / Hdim);
        float rstd = rsqrtf(sq * (1.0f / Hdim) - mean * mean + 1e-5f);
        _Float16* d = dst16rg + (lane >> 1) * 256 + r * 16 + (lane & 1) * 8;
        #pragma unroll
        for (int e = 0; e < 8; ++e) {
            int k = lane * 8 + e;
            float o = (v[e] - mean) * rstd * gam[k] + bet[k];
            gst4<FAST>(pr_ + k, o);
            gsth<FAST>(d + e, o);
        }
    }
}

struct P {
    const float *x, *ewih0, *ewhh0, *ebih0, *ebhh0, *ewih1, *ewhh1, *ebih1, *ebhh1;
    const float *lng, *lnb, *dwih0, *dwhh0, *dbih0, *dbhh0, *dwih1, *dwhh1, *dbih1, *dbhh1;
    const float *fcw, *fcb;
    float* out;
    _Float16 *h0a, *h0b, *h1a, *h1b;
    float *hT0, *hT1, *ybuf;
    int* flags;
};

template<bool FAST>
__device__ __forceinline__ void gru_body(const P& p, _Float16 (&ldsAB)[16384],
                                         float (&ldsAcc)[2][3][272], _Float16 (&ldsOut)[4][256])
{
    const int tid  = threadIdx.x;
    const int wid  = tid >> 6, lane = tid & 63;
    const int role = wid >> 1;              // 0=L0/dec0, 1=GI, 2=GH
    const int pr   = wid & 1;
    const int rg   = blockIdx.x & 15, hp = blockIdx.x >> 4;
    const int cv   = lane & 15, kg = lane >> 4;
    const int hs   = hp * 2 + pr;
    const int hid  = hs * 16 + cv;
    const int row0 = rg * 16;
    const int rb   = kg * 4;
    const int slot = hp * 2 + pr;
    const int ow   = (role == 0) ? pr : 2 + pr;
    const size_t rgbase = (size_t)rg * 32 * 256;

    int* f0  = p.flags + (0 * 16 + rg) * 32;
    int* f1  = p.flags + (1 * 16 + rg) * 32;
    int* fD0 = p.flags + (2 * 16 + rg) * 32;
    int* fD1 = p.flags + (3 * 16 + rg) * 32;
    int* fLN = p.flags + (4 * 16 + rg) * 32;
    int* fY  = p.flags + (5 * 16 + rg) * 32;

    _Float16* h0buf[2] = {p.h0a, p.h0b};
    _Float16* h1buf[2] = {p.h1a, p.h1b};

    // ---- encoder weights -> registers/AGPRs (plain cached loads, read-once) ----
    half8 w0[16], w1[16], w2[16];
    {
        const float* wsP = role == 0 ? p.ewhh0 : (role == 1 ? p.ewih1 : p.ewhh1);
        const float* b0 = wsP + (size_t)hid * Hdim + kg * 8;
        #pragma unroll
        for (int kk = 0; kk < 16; ++kk) {
            w0[kk] = ld_cvt(b0 + kk * 32);
            w1[kk] = ld_cvt(b0 + (size_t)512 * Hdim + kk * 32);
            w2[kk] = ld_cvt(b0 + (size_t)1024 * Hdim + kk * 32);
        }
    }
    float cw_r0 = 0, cw_r1 = 0, cw_z0 = 0, cw_z1 = 0, cw_n0 = 0, cw_n1 = 0;
    float bCr = 0, bCz = 0, bIn = 0, bHn = 0;
    if (role == 0) {
        cw_r0 = p.ewih0[hid * 2];          cw_r1 = p.ewih0[hid * 2 + 1];
        cw_z0 = p.ewih0[(512 + hid) * 2];  cw_z1 = p.ewih0[(512 + hid) * 2 + 1];
        cw_n0 = p.ewih0[(1024 + hid) * 2]; cw_n1 = p.ewih0[(1024 + hid) * 2 + 1];
        bCr = p.ebih0[hid] + p.ebhh0[hid];
        bCz = p.ebih0[512 + hid] + p.ebhh0[512 + hid];
        bIn = p.ebih0[1024 + hid]; bHn = p.ebhh0[1024 + hid];
    } else if (role == 2) {
        bCr = p.ebih1[hid] + p.ebhh1[hid];
        bCz = p.ebih1[512 + hid] + p.ebhh1[512 + hid];
        bIn = p.ebih1[1024 + hid]; bHn = p.ebhh1[1024 + hid];
    }
    float hold[4] = {0.f, 0.f, 0.f, 0.f};

#define LDS_A(BASE, KK) \
    (*(const half8*)&ldsAB[(BASE) + (2 * (KK) + (kg >> 1)) * 256 + cv * 16 + (kg & 1) * 8])
#define STORE_TILE(DSTBUF, HV0, HV1, HV2, HV3)                                   \
    do {                                                                         \
        ldsOut[ow][(rb + 0) * 16 + cv] = (_Float16)(HV0);                        \
        ldsOut[ow][(rb + 1) * 16 + cv] = (_Float16)(HV1);                        \
        ldsOut[ow][(rb + 2) * 16 + cv] = (_Float16)(HV2);                        \
        ldsOut[ow][(rb + 3) * 16 + cv] = (_Float16)(HV3);                        \
        u64 pk_ = *(const u64*)&ldsOut[ow][lane * 4];                            \
        gst8<FAST>((DSTBUF) + rgbase + (size_t)hs * 256 + lane * 4, pk_);        \
    } while (0)

    // ================= encoder: 513 iterations =================
    // iter i: layer0 step i (i<512), layer1 step i-1 (i>=1)
    for (int i = 0; i <= Tlen; ++i) {
        float2 xv[4];
        if (role == 0 && i < Tlen) {
            #pragma unroll
            for (int jj = 0; jj < 4; ++jj)
                xv[jj] = *(const float2*)(p.x + ((size_t)(row0 + rb + jj) * Tlen + i) * 2);
        }
        waitN<FAST, 32>(f1, i - 1);         // h1[i-2] complete
        waitN<FAST, 32>(f0, i);             // h0[i-1] complete
        if constexpr (FAST) acq();          // L1 invalidate before plain data reads
        stage2<FAST>(ldsAB, h0buf[(i - 1) & 1] + rgbase, h1buf[(i - 2) & 1] + rgbase, tid);
        __syncthreads();   // stage visible
        f32x4 a0 = {0,0,0,0}, a1 = {0,0,0,0}, a2 = {0,0,0,0};
        if (role == 2) {
            if (i >= 1) {
                #pragma unroll
                for (int kk = 0; kk < 16; ++kk) {
                    half8 a = LDS_A(8192, kk);
                    a0 = mfma16(a, w0[kk], a0);
                    a1 = mfma16(a, w1[kk], a1);
                    a2 = mfma16(a, w2[kk], a2);
                }
            }
        } else if (role == 0) {
            if (i < Tlen) {
                #pragma unroll
                for (int kk = 0; kk < 16; ++kk) {
                    half8 a = LDS_A(0, kk);
                    a0 = mfma16(a, w0[kk], a0);
                    a1 = mfma16(a, w1[kk], a1);
                    a2 = mfma16(a, w2[kk], a2);
                }
                float hv[4];
                #pragma unroll
                for (int jj = 0; jj < 4; ++jj) {
                    int b = row0 + rb + jj;
                    float x0 = xv[jj].x, x1 = xv[jj].y;
                    float r = sigf(x0 * cw_r0 + x1 * cw_r1 + a0[jj] + bCr);
                    float z = sigf(x0 * cw_z0 + x1 * cw_z1 + a1[jj] + bCz);
                    float n = tanhf(x0 * cw_n0 + x1 * cw_n1 + bIn + r * (a2[jj] + bHn));
                    hv[jj] = (1.0f - z) * n + z * hold[jj];
                    hold[jj] = hv[jj];
                    if (i == Tlen - 1) gst4<FAST>(p.hT0 + (size_t)b * Hdim + hid, hv[jj]);
                }
                STORE_TILE(h0buf[i & 1], hv[0], hv[1], hv[2], hv[3]);
                sigS<FAST>(f0 + slot, i + 1);
            }
        } else { // GI: gi = y0[i-1] @ wih1^T
            if (i >= 1) {
                #pragma unroll
                for (int kk = 0; kk < 16; ++kk) {
                    half8 a = LDS_A(0, kk);
                    a0 = mfma16(a, w0[kk], a0);
                    a1 = mfma16(a, w1[kk], a1);
                    a2 = mfma16(a, w2[kk], a2);
                }
                #pragma unroll
                for (int jj = 0; jj < 4; ++jj) {
                    int rr = (rb + jj) * 17 + cv;
                    ldsAcc[pr][0][rr] = a0[jj];
                    ldsAcc[pr][1][rr] = a1[jj];
                    ldsAcc[pr][2][rr] = a2[jj];
                }
            }
        }
        __syncthreads();   // ldsAcc visible
        if (role == 2 && i >= 1) {
            float hv[4];
            #pragma unroll
            for (int jj = 0; jj < 4; ++jj) {
                int b = row0 + rb + jj;
                int rr = (rb + jj) * 17 + cv;
                float gr = ldsAcc[pr][0][rr];
                float gz = ldsAcc[pr][1][rr];
                float gn = ldsAcc[pr][2][rr];
                float r = sigf(gr + a0[jj] + bCr);
                float z = sigf(gz + a1[jj] + bCz);
                float n = tanhf(gn + bIn + r * (a2[jj] + bHn));
                hv[jj] = (1.0f - z) * n + z * hold[jj];
                hold[jj] = hv[jj];
                if (i == Tlen) gst4<FAST>(p.hT1 + (size_t)b * Hdim + hid, hv[jj]);
            }
            STORE_TILE(h1buf[(i - 1) & 1], hv[0], hv[1], hv[2], hv[3]);
            sigS<FAST>(f1 + slot, i);      // h1[i-1] done
        }
    }

    // ================= LayerNorm =================
    if (hp == 0 && wid == 0) {
        waitN<FAST, 32>(f0, Tlen);
        waitN<FAST, 32>(f1, Tlen);
        if constexpr (FAST) acq();
        ln_rows<FAST>(p.hT0, h0buf[1] + rgbase, p.lng, p.lnb, row0, lane);
        if (lane < 16) {
            int b = row0 + lane;
            gst4<FAST>(p.ybuf + b, p.x[((size_t)b * Tlen + (Tlen - 1)) * 2 + 1]);
        }
        sigS<FAST>(fLN + 0, 1);
    }
    if (hp == 0 && wid == 4) {
        waitN<FAST, 32>(f1, Tlen);
        if constexpr (FAST) acq();
        ln_rows<FAST>(p.hT1, h1buf[1] + rgbase, p.lng, p.lnb, row0, lane);
        sigS<FAST>(fLN + 1, 1);
    }

    // ---- decoder weights ----
    {
        const float* wsP = role == 0 ? p.dwhh0 : (role == 1 ? p.dwih1 : p.dwhh1);
        const float* b0 = wsP + (size_t)hid * Hdim + kg * 8;
        #pragma unroll
        for (int kk = 0; kk < 16; ++kk) {
            w0[kk] = ld_cvt(b0 + kk * 32);
            w1[kk] = ld_cvt(b0 + (size_t)512 * Hdim + kk * 32);
            w2[kk] = ld_cvt(b0 + (size_t)1024 * Hdim + kk * 32);
        }
    }
    if (role == 0) {
        cw_r0 = p.dwih0[hid]; cw_z0 = p.dwih0[512 + hid]; cw_n0 = p.dwih0[1024 + hid];
        bCr = p.dbih0[hid] + p.dbhh0[hid];
        bCz = p.dbih0[512 + hid] + p.dbhh0[512 + hid];
        bIn = p.dbih0[1024 + hid]; bHn = p.dbhh0[1024 + hid];
    } else if (role == 2) {
        bCr = p.dbih1[hid] + p.dbhh1[hid];
        bCz = p.dbih1[512 + hid] + p.dbhh1[512 + hid];
        bIn = p.dbih1[1024 + hid]; bHn = p.dbhh1[1024 + hid];
    }
    float fw[8] = {0,0,0,0,0,0,0,0};
    float fb = 0.f;
    const bool is_fc = (hp == 0 && wid == 4);
    if (is_fc) {
        #pragma unroll
        for (int e = 0; e < 8; ++e) fw[e] = p.fcw[lane * 8 + e];
        fb = p.fcb[0];
    }
    waitN<FAST, 2>(fLN, 1);
    if constexpr (FAST) acq();
    if (role == 0 || role == 2) {
        const float* hTsrc = (role == 0) ? p.hT0 : p.hT1;
        #pragma unroll
        for (int jj = 0; jj < 4; ++jj)
            hold[jj] = gld4<FAST>(hTsrc + (size_t)(row0 + rb + jj) * Hdim + hid);
    }

    // ================= decoder: 10 steps =================
    for (int t = 0; t < OUTL; ++t) {
        waitN<FAST, 32>(fD1, t);
        waitN<FAST, 32>(fD0, t);
        if (role == 0) waitN<FAST, 1>(fY, t);
        if constexpr (FAST) acq();
        stage2<FAST>(ldsAB, h0buf[(t - 1) & 1] + rgbase, h1buf[(t - 1) & 1] + rgbase, tid);
        __syncthreads();
        f32x4 a0 = {0,0,0,0}, a1 = {0,0,0,0}, a2 = {0,0,0,0};
        if (role == 0) {
            float yvv[4];
            #pragma unroll
            for (int jj = 0; jj < 4; ++jj) yvv[jj] = gld4<FAST>(p.ybuf + row0 + rb + jj);
            #pragma unroll
            for (int kk = 0; kk < 16; ++kk) {
                half8 a = LDS_A(0, kk);
                a0 = mfma16(a, w0[kk], a0);
                a1 = mfma16(a, w1[kk], a1);
                a2 = mfma16(a, w2[kk], a2);
            }
            float hv[4];
            #pragma unroll
            for (int jj = 0; jj < 4; ++jj) {
                float yv = yvv[jj];
                float r = sigf(yv * cw_r0 + a0[jj] + bCr);
                float z = sigf(yv * cw_z0 + a1[jj] + bCz);
                float n = tanhf(yv * cw_n0 + bIn + r * (a2[jj] + bHn));
                hv[jj] = (1.0f - z) * n + z * hold[jj];
                hold[jj] = hv[jj];
            }
            STORE_TILE(h0buf[t & 1], hv[0], hv[1], hv[2], hv[3]);
            sigS<FAST>(fD0 + slot, t + 1);
        } else if (role == 1) {
            waitN<FAST, 32>(fD0, t + 1);    // fresh h0dec[t]
            if constexpr (FAST) acq();
            const _Float16* agb = h0buf[t & 1] + rgbase;
            #pragma unroll
            for (int kk = 0; kk < 16; ++kk) {
                const _Float16* pa = agb + (2 * kk + (kg >> 1)) * 256 + cv * 16 + (kg & 1) * 8;
                half8 q = gld16h<FAST>(pa);
                a0 = mfma16(q, w0[kk], a0);
                a1 = mfma16(q, w1[kk], a1);
                a2 = mfma16(q, w2[kk], a2);
            }
            #pragma unroll
            for (int jj = 0; jj < 4; ++jj) {
                int rr = (rb + jj) * 17 + cv;
                ldsAcc[pr][0][rr] = a0[jj];
                ldsAcc[pr][1][rr] = a1[jj];
                ldsAcc[pr][2][rr] = a2[jj];
            }
        } else {
            #pragma unroll
            for (int kk = 0; kk < 16; ++kk) {
                half8 a = LDS_A(8192, kk);
                a0 = mfma16(a, w0[kk], a0);
                a1 = mfma16(a, w1[kk], a1);
                a2 = mfma16(a, w2[kk], a2);
            }
        }
        __syncthreads();
        if (role == 2) {
            float hv[4];
            #pragma unroll
            for (int jj = 0; jj < 4; ++jj) {
                int rr = (rb + jj) * 17 + cv;
                float gr = ldsAcc[pr][0][rr];
                float gz = ldsAcc[pr][1][rr];
                float gn = ldsAcc[pr][2][rr];
                float r = sigf(gr + a0[jj] + bCr);
                float z = sigf(gz + a1[jj] + bCz);
                float n = tanhf(gn + bIn + r * (a2[jj] + bHn));
                hv[jj] = (1.0f - z) * n + z * hold[jj];
                hold[jj] = hv[jj];
            }
            STORE_TILE(h1buf[t & 1], hv[0], hv[1], hv[2], hv[3]);
            sigS<FAST>(fD1 + slot, t + 1);
            if (is_fc) {
                waitN<FAST, 32>(fD1, t + 1);
                if constexpr (FAST) acq();
                const _Float16* hb = h1buf[t & 1] + rgbase;
                #pragma unroll 1
                for (int r2 = 0; r2 < 16; ++r2) {
                    const _Float16* hp8 = hb + (lane >> 1) * 256 + r2 * 16 + (lane & 1) * 8;
                    half8 hv8 = gld16h<FAST>(hp8);
                    float pa = 0.f;
                    #pragma unroll
                    for (int e = 0; e < 8; ++e) pa += (float)hv8[e] * fw[e];
                    #pragma unroll
                    for (int m = 1; m < 64; m <<= 1) pa += __shfl_xor(pa, m);
                    if (lane == 0) {
                        int b = row0 + r2;
                        float yv2 = pa + fb;
                        gst4<FAST>(p.ybuf + b, yv2);
                        p.out[(size_t)b * OUTL + t] = yv2;
                    }
                }
                sigS<FAST>(fY, t + 1);
            }
        }
    }
#undef STORE_TILE
#undef LDS_A
}

__global__ __launch_bounds__(384, 1) void gru_all(
    const float* x,
    const float* ewih0, const float* ewhh0, const float* ebih0, const float* ebhh0,
    const float* ewih1, const float* ewhh1, const float* ebih1, const float* ebhh1,
    const float* lng,   const float* lnb,
    const float* dwih0, const float* dwhh0, const float* dbih0, const float* dbhh0,
    const float* dwih1, const float* dwhh1, const float* dbih1, const float* dbhh1,
    const float* fcw,   const float* fcb,
    float* out,
    _Float16* h0a, _Float16* h0b, _Float16* h1a, _Float16* h1b,
    float* hT0, float* hT1, float* ybuf, int* flags)
{
    __shared__ _Float16 ldsAB[16384];
    __shared__ float    ldsAcc[2][3][272];
    __shared__ _Float16 ldsOut[4][256];

    P p{x, ewih0, ewhh0, ebih0, ebhh0, ewih1, ewhh1, ebih1, ebhh1,
        lng, lnb, dwih0, dwhh0, dbih0, dbhh0, dwih1, dwhh1, dbih1, dbhh1,
        fcw, fcb, out, h0a, h0b, h1a, h1b, hT0, hT1, ybuf, flags};

    const int tid  = threadIdx.x;
    const int lane = tid & 63;
    const int rg   = blockIdx.x & 15, hp = blockIdx.x >> 4;

    // ---- runtime XCD-uniformity gate (agent-scope, r5-proven prims only) ----
    int* xt = flags + 6 * 16 * 32 + rg * 16;
    int xcc = 0;
    asm volatile("s_getreg_b32 %0, hwreg(HW_REG_XCC_ID)" : "=s"(xcc));
    if (tid == 0) a_sti(xt + hp, xcc + 1);
    bool fast;
    {
        int* pp = xt + (lane & 15);
        int v;
        while (true) {
            v = a_ldi(pp);
            if (__all(v >= 1)) break;
            __builtin_amdgcn_s_sleep(1);
        }
        int v0 = __shfl(v, 0);
        fast = __all(v == v0);
    }
    asm volatile("" ::: "memory");

    if (fast) gru_body<true>(p, ldsAB, ldsAcc, ldsOut);
    else      gru_body<false>(p, ldsAB, ldsAcc, ldsOut);
}

extern "C" void kernel_launch(void* const* d_in, const int* in_sizes, int n_in,
                              void* d_out, int out_size, void* d_ws, size_t ws_size,
                              hipStream_t stream)
{
    (void)in_sizes; (void)n_in; (void)out_size; (void)ws_size;
    char* ws = (char*)d_ws;
    size_t off = 0;
    auto alloc = [&](size_t bytes) -> void* {
        void* pv = ws + off;
        off += (bytes + 255) & ~(size_t)255;
        return pv;
    };

    // [flags(+xcd table)][h0a][h0b][h1a][h1b] zeroed each call; [hT0][hT1][ybuf]
    int* flags = (int*)alloc((6 * 16 * 32 + 16 * 16) * sizeof(int));
    const size_t HB = (size_t)Bsz * Hdim;
    _Float16* h0a = (_Float16*)alloc(HB * 2);
    _Float16* h0b = (_Float16*)alloc(HB * 2);
    _Float16* h1a = (_Float16*)alloc(HB * 2);
    _Float16* h1b = (_Float16*)alloc(HB * 2);
    size_t zbytes = off;
    float* hT0  = (float*)alloc(HB * 4);
    float* hT1  = (float*)alloc(HB * 4);
    float* ybuf = (float*)alloc(Bsz * 4);

    hipMemsetAsync(d_ws, 0, zbytes, stream);

    gru_all<<<256, 384, 0, stream>>>(
        (const float*)d_in[0],
        (const float*)d_in[1],  (const float*)d_in[2],
        (const float*)d_in[3],  (const float*)d_in[4],
        (const float*)d_in[5],  (const float*)d_in[6],
        (const float*)d_in[7],  (const float*)d_in[8],
        (const float*)d_in[9],  (const float*)d_in[10],
        (const float*)d_in[11], (const float*)d_in[12],
        (const float*)d_in[13], (const float*)d_in[14],
        (const float*)d_in[15], (const float*)d_in[16],
        (const float*)d_in[17], (const float*)d_in[18],
        (const float*)d_in[19], (const float*)d_in[20],
        (float*)d_out, h0a, h0b, h1a, h1b, hT0, hT1, ybuf, flags);
}

// Round 10
// 5564.346 us; speedup vs baseline: 5.7962x; 5.7962x over previous
//
#include <hip/hip_runtime.h>
#include <math.h>

// Seq2SeqGRU persistent kernel. B=256, T=512, H=512, OUT=10.
// 256 WGs x 384 threads. WG = (rowgroup rg = blockIdx&15, hid-part hp = blockIdx>>4).
// All cross-WG traffic is rg-internal; round-robin dispatch puts a rg's 16 WGs on
// one XCD (XCC_ID-gated). FAST path: plain stores (write-through L1 -> shared XCD
// L2) + plain loads after BUFFER_INV SC0 (L1-ONLY invalidate, ~free) -> L2-served
// exchange. r9's mistake was agent fences (L2 invalidate) in the poll loop.
// Flags: dual store (plain L2 + sc1 MALL); polls keep an sc1 progress leg -> no hang.
// SLOW path (gate fail) = r7's proven all-sc1 scheme.

#define Hdim 512
#define Bsz  256
#define Tlen 512
#define OUTL 10

typedef _Float16 half8 __attribute__((ext_vector_type(8)));
typedef float    f32x4 __attribute__((ext_vector_type(4)));
typedef unsigned long long u64;

__device__ __forceinline__ f32x4 mfma16(half8 a, half8 b, f32x4 c) {
    return __builtin_amdgcn_mfma_f32_16x16x32_f16(a, b, c, 0, 0, 0);
}
__device__ __forceinline__ float sigf(float v) { return 1.0f / (1.0f + __expf(-v)); }
__device__ __forceinline__ half8 h8(u64 lo, u64 hi) {
    union { u64 u[2]; half8 h; } t; t.u[0] = lo; t.u[1] = hi; return t.h;
}

// ---- agent-scope relaxed prims (sc1; r5-r7 proven, cross-XCD safe) ----
__device__ __forceinline__ u64 a_ld8(const void* p) {
    return __hip_atomic_load((const u64*)p, __ATOMIC_RELAXED, __HIP_MEMORY_SCOPE_AGENT); }
__device__ __forceinline__ float a_ld4(const void* p) {
    return __hip_atomic_load((const float*)p, __ATOMIC_RELAXED, __HIP_MEMORY_SCOPE_AGENT); }
__device__ __forceinline__ int a_ldi(const int* p) {
    return __hip_atomic_load(p, __ATOMIC_RELAXED, __HIP_MEMORY_SCOPE_AGENT); }
__device__ __forceinline__ void a_st8(void* p, u64 v) {
    __hip_atomic_store((u64*)p, v, __ATOMIC_RELAXED, __HIP_MEMORY_SCOPE_AGENT); }
__device__ __forceinline__ void a_st4(void* p, float v) {
    __hip_atomic_store((float*)p, v, __ATOMIC_RELAXED, __HIP_MEMORY_SCOPE_AGENT); }
__device__ __forceinline__ void a_st2(void* p, unsigned short v) {
    __hip_atomic_store((unsigned short*)p, v, __ATOMIC_RELAXED, __HIP_MEMORY_SCOPE_AGENT); }
__device__ __forceinline__ void a_sti(int* p, int v) {
    __hip_atomic_store(p, v, __ATOMIC_RELAXED, __HIP_MEMORY_SCOPE_AGENT); }

// L1-ONLY invalidate (sc0). Does NOT touch L2 (sc1 variant = r9's 5x regression).
// "memory" clobber orders surrounding plain loads/stores around it.
__device__ __forceinline__ void l1inv() {
    asm volatile("buffer_inv sc0" ::: "memory");
}

// ---- templated data accessors: FAST = plain (L2-local), SLOW = sc1 agent ----
template<bool FAST> __device__ __forceinline__ float gld4(const float* p) {
    if constexpr (FAST) return *p; else return a_ld4(p);
}
template<bool FAST> __device__ __forceinline__ void gst4(float* p, float v) {
    if constexpr (FAST) *p = v; else a_st4(p, v);
}
template<bool FAST> __device__ __forceinline__ void gst8(_Float16* p, u64 v) {
    if constexpr (FAST) *(u64*)p = v; else a_st8(p, v);
}
template<bool FAST> __device__ __forceinline__ void gsth(_Float16* p, float v) {
    if constexpr (FAST) *p = (_Float16)v;
    else a_st2(p, __builtin_bit_cast(unsigned short, (_Float16)v));
}
template<bool FAST> __device__ __forceinline__ half8 gld16h(const _Float16* p) {
    if constexpr (FAST) return *(const half8*)p;
    else return h8(a_ld8(p), a_ld8(p + 4));
}

// signal: drain stores (FAST: to local L2; SLOW: to fabric), then flag store(s).
template<bool FAST>
__device__ __forceinline__ void sigS(int* slot, int val) {
    asm volatile("s_waitcnt vmcnt(0)" ::: "memory");
    if ((threadIdx.x & 63) == 0) {
        if constexpr (FAST) *(volatile int*)slot = val;   // L2-visible leg
        a_sti(slot, val);                                 // MALL leg (progress guarantee)
    }
}
// wait: FAST = L1-inv + plain probes (L2-served) with periodic sc1 probe; SLOW = r7.
template<bool FAST, int NS>
__device__ __forceinline__ void waitN(int* base, int target) {
    if (target <= 0) return;
    int* p = base + ((threadIdx.x & 63) % NS);
    while (true) {
        if constexpr (FAST) {
            bool ok = false;
            #pragma unroll 1
            for (int k = 0; k < 8; ++k) {
                l1inv();
                int v = *(volatile int*)p;
                if (__all(v >= target)) { ok = true; break; }
            }
            if (ok) break;
        }
        int v2 = a_ldi(p);                 // guaranteed-progress leg
        if (__all(v2 >= target)) break;
        __builtin_amdgcn_s_sleep(1);
    }
    asm volatile("" ::: "memory");
}

__device__ __forceinline__ half8 ld_cvt(const float* p) {
    float4 a = *(const float4*)p;
    float4 b = *(const float4*)(p + 4);
    half8 v;
    v[0]=(_Float16)a.x; v[1]=(_Float16)a.y; v[2]=(_Float16)a.z; v[3]=(_Float16)a.w;
    v[4]=(_Float16)b.x; v[5]=(_Float16)b.y; v[6]=(_Float16)b.z; v[7]=(_Float16)b.w;
    return v;
}

// Stage both contiguous 16KB rg blocks -> LDS (linear, tile-major layout).
template<bool FAST>
__device__ __forceinline__ void stage2(_Float16* ldsAB, const _Float16* sA,
                                       const _Float16* sB, int tid) {
    if constexpr (FAST) {
        #pragma unroll
        for (int u = 0; u < 3; ++u) {
            int c = tid + u * 384;
            if (c < 1024) {
                half8 vb = *(const half8*)(sB + c * 8);
                half8 va = *(const half8*)(sA + c * 8);
                *(half8*)&ldsAB[8192 + c * 8] = vb;
                *(half8*)&ldsAB[c * 8] = va;
            }
        }
    } else {
        u64 tvB[6], tvA[6];
        #pragma unroll
        for (int u = 0; u < 6; ++u) {
            int c = tid + u * 384;
            if (c < 2048) { tvB[u] = a_ld8(sB + c * 4); tvA[u] = a_ld8(sA + c * 4); }
        }
        #pragma unroll
        for (int u = 0; u < 6; ++u) {
            int c = tid + u * 384;
            if (c < 2048) {
                *(u64*)&ldsAB[8192 + c * 4] = tvB[u];
                *(u64*)&ldsAB[c * 4] = tvA[u];
            }
        }
    }
}

// LayerNorm of 16 rows (one wave). hT f32 in/out; dst16rg tile-major f16 copy.
template<bool FAST>
__device__ void ln_rows(float* hT, _Float16* dst16rg, const float* gam, const float* bet,
                        int row0, int lane) {
    #pragma unroll 1
    for (int r = 0; r < 16; ++r) {
        float* pr_ = hT + (size_t)(row0 + r) * Hdim;
        float v[8];
        if constexpr (FAST) {
            float4 v0 = *(const float4*)(pr_ + lane * 8);
            float4 v1 = *(const float4*)(pr_ + lane * 8 + 4);
            v[0]=v0.x; v[1]=v0.y; v[2]=v0.z; v[3]=v0.w;
            v[4]=v1.x; v[5]=v1.y; v[6]=v1.z; v[7]=v1.w;
        } else {
            #pragma unroll
            for (int e = 0; e < 4; ++e) {
                union { u64 u; float f[2]; } c;
                c.u = a_ld8(pr_ + lane * 8 + e * 2);
                v[2*e] = c.f[0]; v[2*e+1] = c.f[1];
            }
        }
        float s = 0.f, sq = 0.f;
        #pragma unroll
        for (int e = 0; e < 8; ++e) { s += v[e]; sq += v[e] * v[e]; }
        #pragma unroll
        for (int m = 1; m < 64; m <<= 1) { s += __shfl_xor(s, m); sq += __shfl_xor(sq, m); }
        float mean = s * (1.0f / Hdim);
        float rstd = rsqrtf(sq * (1.0f / Hdim) - mean * mean + 1e-5f);
        _Float16* d = dst16rg + (lane >> 1) * 256 + r * 16 + (lane & 1) * 8;
        #pragma unroll
        for (int e = 0; e < 8; ++e) {
            int k = lane * 8 + e;
            float o = (v[e] - mean) * rstd * gam[k] + bet[k];
            gst4<FAST>(pr_ + k, o);
            gsth<FAST>(d + e, o);
        }
    }
}

struct P {
    const float *x, *ewih0, *ewhh0, *ebih0, *ebhh0, *ewih1, *ewhh1, *ebih1, *ebhh1;
    const float *lng, *lnb, *dwih0, *dwhh0, *dbih0, *dbhh0, *dwih1, *dwhh1, *dbih1, *dbhh1;
    const float *fcw, *fcb;
    float* out;
    _Float16 *h0a, *h0b, *h1a, *h1b;
    float *hT0, *hT1, *ybuf;
    int* flags;
};

template<bool FAST>
__device__ __forceinline__ void gru_body(const P& p, _Float16 (&ldsAB)[16384],
                                         float (&ldsAcc)[2][3][272], _Float16 (&ldsOut)[4][256])
{
    const int tid  = threadIdx.x;
    const int wid  = tid >> 6, lane = tid & 63;
    const int role = wid >> 1;              // 0=L0/dec0, 1=GI, 2=GH
    const int pr   = wid & 1;
    const int rg   = blockIdx.x & 15, hp = blockIdx.x >> 4;
    const int cv   = lane & 15, kg = lane >> 4;
    const int hs   = hp * 2 + pr;
    const int hid  = hs * 16 + cv;
    const int row0 = rg * 16;
    const int rb   = kg * 4;
    const int slot = hp * 2 + pr;
    const int ow   = (role == 0) ? pr : 2 + pr;
    const size_t rgbase = (size_t)rg * 32 * 256;

    int* f0  = p.flags + (0 * 16 + rg) * 32;
    int* f1  = p.flags + (1 * 16 + rg) * 32;
    int* fD0 = p.flags + (2 * 16 + rg) * 32;
    int* fD1 = p.flags + (3 * 16 + rg) * 32;
    int* fLN = p.flags + (4 * 16 + rg) * 32;
    int* fY  = p.flags + (5 * 16 + rg) * 32;

    _Float16* h0buf[2] = {p.h0a, p.h0b};
    _Float16* h1buf[2] = {p.h1a, p.h1b};

    // ---- encoder weights -> registers/AGPRs (plain cached loads, read-once) ----
    half8 w0[16], w1[16], w2[16];
    {
        const float* wsP = role == 0 ? p.ewhh0 : (role == 1 ? p.ewih1 : p.ewhh1);
        const float* b0 = wsP + (size_t)hid * Hdim + kg * 8;
        #pragma unroll
        for (int kk = 0; kk < 16; ++kk) {
            w0[kk] = ld_cvt(b0 + kk * 32);
            w1[kk] = ld_cvt(b0 + (size_t)512 * Hdim + kk * 32);
            w2[kk] = ld_cvt(b0 + (size_t)1024 * Hdim + kk * 32);
        }
    }
    float cw_r0 = 0, cw_r1 = 0, cw_z0 = 0, cw_z1 = 0, cw_n0 = 0, cw_n1 = 0;
    float bCr = 0, bCz = 0, bIn = 0, bHn = 0;
    if (role == 0) {
        cw_r0 = p.ewih0[hid * 2];          cw_r1 = p.ewih0[hid * 2 + 1];
        cw_z0 = p.ewih0[(512 + hid) * 2];  cw_z1 = p.ewih0[(512 + hid) * 2 + 1];
        cw_n0 = p.ewih0[(1024 + hid) * 2]; cw_n1 = p.ewih0[(1024 + hid) * 2 + 1];
        bCr = p.ebih0[hid] + p.ebhh0[hid];
        bCz = p.ebih0[512 + hid] + p.ebhh0[512 + hid];
        bIn = p.ebih0[1024 + hid]; bHn = p.ebhh0[1024 + hid];
    } else if (role == 2) {
        bCr = p.ebih1[hid] + p.ebhh1[hid];
        bCz = p.ebih1[512 + hid] + p.ebhh1[512 + hid];
        bIn = p.ebih1[1024 + hid]; bHn = p.ebhh1[1024 + hid];
    }
    float hold[4] = {0.f, 0.f, 0.f, 0.f};

#define LDS_A(BASE, KK) \
    (*(const half8*)&ldsAB[(BASE) + (2 * (KK) + (kg >> 1)) * 256 + cv * 16 + (kg & 1) * 8])
#define STORE_TILE(DSTBUF, HV0, HV1, HV2, HV3)                                   \
    do {                                                                         \
        ldsOut[ow][(rb + 0) * 16 + cv] = (_Float16)(HV0);                        \
        ldsOut[ow][(rb + 1) * 16 + cv] = (_Float16)(HV1);                        \
        ldsOut[ow][(rb + 2) * 16 + cv] = (_Float16)(HV2);                        \
        ldsOut[ow][(rb + 3) * 16 + cv] = (_Float16)(HV3);                        \
        u64 pk_ = *(const u64*)&ldsOut[ow][lane * 4];                            \
        gst8<FAST>((DSTBUF) + rgbase + (size_t)hs * 256 + lane * 4, pk_);        \
    } while (0)

    // ================= encoder: 513 iterations =================
    // iter i: layer0 step i (i<512), layer1 step i-1 (i>=1)
    for (int i = 0; i <= Tlen; ++i) {
        float2 xv[4];
        if (role == 0 && i < Tlen) {
            #pragma unroll
            for (int jj = 0; jj < 4; ++jj)
                xv[jj] = *(const float2*)(p.x + ((size_t)(row0 + rb + jj) * Tlen + i) * 2);
        }
        waitN<FAST, 32>(f1, i - 1);         // h1[i-2] complete
        waitN<FAST, 32>(f0, i);             // h0[i-1] complete
        if constexpr (FAST) l1inv();        // drop stale L1 lines; L2 is fresh
        stage2<FAST>(ldsAB, h0buf[(i - 1) & 1] + rgbase, h1buf[(i - 2) & 1] + rgbase, tid);
        __syncthreads();   // stage visible
        f32x4 a0 = {0,0,0,0}, a1 = {0,0,0,0}, a2 = {0,0,0,0};
        if (role == 2) {
            if (i >= 1) {
                #pragma unroll
                for (int kk = 0; kk < 16; ++kk) {
                    half8 a = LDS_A(8192, kk);
                    a0 = mfma16(a, w0[kk], a0);
                    a1 = mfma16(a, w1[kk], a1);
                    a2 = mfma16(a, w2[kk], a2);
                }
            }
        } else if (role == 0) {
            if (i < Tlen) {
                #pragma unroll
                for (int kk = 0; kk < 16; ++kk) {
                    half8 a = LDS_A(0, kk);
                    a0 = mfma16(a, w0[kk], a0);
                    a1 = mfma16(a, w1[kk], a1);
                    a2 = mfma16(a, w2[kk], a2);
                }
                float hv[4];
                #pragma unroll
                for (int jj = 0; jj < 4; ++jj) {
                    int b = row0 + rb + jj;
                    float x0 = xv[jj].x, x1 = xv[jj].y;
                    float r = sigf(x0 * cw_r0 + x1 * cw_r1 + a0[jj] + bCr);
                    float z = sigf(x0 * cw_z0 + x1 * cw_z1 + a1[jj] + bCz);
                    float n = tanhf(x0 * cw_n0 + x1 * cw_n1 + bIn + r * (a2[jj] + bHn));
                    hv[jj] = (1.0f - z) * n + z * hold[jj];
                    hold[jj] = hv[jj];
                    if (i == Tlen - 1) gst4<FAST>(p.hT0 + (size_t)b * Hdim + hid, hv[jj]);
                }
                STORE_TILE(h0buf[i & 1], hv[0], hv[1], hv[2], hv[3]);
                sigS<FAST>(f0 + slot, i + 1);
            }
        } else { // GI: gi = y0[i-1] @ wih1^T
            if (i >= 1) {
                #pragma unroll
                for (int kk = 0; kk < 16; ++kk) {
                    half8 a = LDS_A(0, kk);
                    a0 = mfma16(a, w0[kk], a0);
                    a1 = mfma16(a, w1[kk], a1);
                    a2 = mfma16(a, w2[kk], a2);
                }
                #pragma unroll
                for (int jj = 0; jj < 4; ++jj) {
                    int rr = (rb + jj) * 17 + cv;
                    ldsAcc[pr][0][rr] = a0[jj];
                    ldsAcc[pr][1][rr] = a1[jj];
                    ldsAcc[pr][2][rr] = a2[jj];
                }
            }
        }
        __syncthreads();   // ldsAcc visible
        if (role == 2 && i >= 1) {
            float hv[4];
            #pragma unroll
            for (int jj = 0; jj < 4; ++jj) {
                int b = row0 + rb + jj;
                int rr = (rb + jj) * 17 + cv;
                float gr = ldsAcc[pr][0][rr];
                float gz = ldsAcc[pr][1][rr];
                float gn = ldsAcc[pr][2][rr];
                float r = sigf(gr + a0[jj] + bCr);
                float z = sigf(gz + a1[jj] + bCz);
                float n = tanhf(gn + bIn + r * (a2[jj] + bHn));
                hv[jj] = (1.0f - z) * n + z * hold[jj];
                hold[jj] = hv[jj];
                if (i == Tlen) gst4<FAST>(p.hT1 + (size_t)b * Hdim + hid, hv[jj]);
            }
            STORE_TILE(h1buf[(i - 1) & 1], hv[0], hv[1], hv[2], hv[3]);
            sigS<FAST>(f1 + slot, i);      // h1[i-1] done
        }
    }

    // ================= LayerNorm =================
    if (hp == 0 && wid == 0) {
        waitN<FAST, 32>(f0, Tlen);
        waitN<FAST, 32>(f1, Tlen);
        if constexpr (FAST) l1inv();
        ln_rows<FAST>(p.hT0, h0buf[1] + rgbase, p.lng, p.lnb, row0, lane);
        if (lane < 16) {
            int b = row0 + lane;
            gst4<FAST>(p.ybuf + b, p.x[((size_t)b * Tlen + (Tlen - 1)) * 2 + 1]);
        }
        sigS<FAST>(fLN + 0, 1);
    }
    if (hp == 0 && wid == 4) {
        waitN<FAST, 32>(f1, Tlen);
        if constexpr (FAST) l1inv();
        ln_rows<FAST>(p.hT1, h1buf[1] + rgbase, p.lng, p.lnb, row0, lane);
        sigS<FAST>(fLN + 1, 1);
    }

    // ---- decoder weights ----
    {
        const float* wsP = role == 0 ? p.dwhh0 : (role == 1 ? p.dwih1 : p.dwhh1);
        const float* b0 = wsP + (size_t)hid * Hdim + kg * 8;
        #pragma unroll
        for (int kk = 0; kk < 16; ++kk) {
            w0[kk] = ld_cvt(b0 + kk * 32);
            w1[kk] = ld_cvt(b0 + (size_t)512 * Hdim + kk * 32);
            w2[kk] = ld_cvt(b0 + (size_t)1024 * Hdim + kk * 32);
        }
    }
    if (role == 0) {
        cw_r0 = p.dwih0[hid]; cw_z0 = p.dwih0[512 + hid]; cw_n0 = p.dwih0[1024 + hid];
        bCr = p.dbih0[hid] + p.dbhh0[hid];
        bCz = p.dbih0[512 + hid] + p.dbhh0[512 + hid];
        bIn = p.dbih0[1024 + hid]; bHn = p.dbhh0[1024 + hid];
    } else if (role == 2) {
        bCr = p.dbih1[hid] + p.dbhh1[hid];
        bCz = p.dbih1[512 + hid] + p.dbhh1[512 + hid];
        bIn = p.dbih1[1024 + hid]; bHn = p.dbhh1[1024 + hid];
    }
    float fw[8] = {0,0,0,0,0,0,0,0};
    float fb = 0.f;
    const bool is_fc = (hp == 0 && wid == 4);
    if (is_fc) {
        #pragma unroll
        for (int e = 0; e < 8; ++e) fw[e] = p.fcw[lane * 8 + e];
        fb = p.fcb[0];
    }
    waitN<FAST, 2>(fLN, 1);
    if constexpr (FAST) l1inv();
    if (role == 0 || role == 2) {
        const float* hTsrc = (role == 0) ? p.hT0 : p.hT1;
        #pragma unroll
        for (int jj = 0; jj < 4; ++jj)
            hold[jj] = gld4<FAST>(hTsrc + (size_t)(row0 + rb + jj) * Hdim + hid);
    }

    // ================= decoder: 10 steps =================
    for (int t = 0; t < OUTL; ++t) {
        waitN<FAST, 32>(fD1, t);
        waitN<FAST, 32>(fD0, t);
        if (role == 0) waitN<FAST, 1>(fY, t);
        if constexpr (FAST) l1inv();
        stage2<FAST>(ldsAB, h0buf[(t - 1) & 1] + rgbase, h1buf[(t - 1) & 1] + rgbase, tid);
        __syncthreads();
        f32x4 a0 = {0,0,0,0}, a1 = {0,0,0,0}, a2 = {0,0,0,0};
        if (role == 0) {
            float yvv[4];
            #pragma unroll
            for (int jj = 0; jj < 4; ++jj) yvv[jj] = gld4<FAST>(p.ybuf + row0 + rb + jj);
            #pragma unroll
            for (int kk = 0; kk < 16; ++kk) {
                half8 a = LDS_A(0, kk);
                a0 = mfma16(a, w0[kk], a0);
                a1 = mfma16(a, w1[kk], a1);
                a2 = mfma16(a, w2[kk], a2);
            }
            float hv[4];
            #pragma unroll
            for (int jj = 0; jj < 4; ++jj) {
                float yv = yvv[jj];
                float r = sigf(yv * cw_r0 + a0[jj] + bCr);
                float z = sigf(yv * cw_z0 + a1[jj] + bCz);
                float n = tanhf(yv * cw_n0 + bIn + r * (a2[jj] + bHn));
                hv[jj] = (1.0f - z) * n + z * hold[jj];
                hold[jj] = hv[jj];
            }
            STORE_TILE(h0buf[t & 1], hv[0], hv[1], hv[2], hv[3]);
            sigS<FAST>(fD0 + slot, t + 1);
        } else if (role == 1) {
            waitN<FAST, 32>(fD0, t + 1);    // fresh h0dec[t]
            if constexpr (FAST) l1inv();
            const _Float16* agb = h0buf[t & 1] + rgbase;
            #pragma unroll
            for (int kk = 0; kk < 16; ++kk) {
                const _Float16* pa = agb + (2 * kk + (kg >> 1)) * 256 + cv * 16 + (kg & 1) * 8;
                half8 q = gld16h<FAST>(pa);
                a0 = mfma16(q, w0[kk], a0);
                a1 = mfma16(q, w1[kk], a1);
                a2 = mfma16(q, w2[kk], a2);
            }
            #pragma unroll
            for (int jj = 0; jj < 4; ++jj) {
                int rr = (rb + jj) * 17 + cv;
                ldsAcc[pr][0][rr] = a0[jj];
                ldsAcc[pr][1][rr] = a1[jj];
                ldsAcc[pr][2][rr] = a2[jj];
            }
        } else {
            #pragma unroll
            for (int kk = 0; kk < 16; ++kk) {
                half8 a = LDS_A(8192, kk);
                a0 = mfma16(a, w0[kk], a0);
                a1 = mfma16(a, w1[kk], a1);
                a2 = mfma16(a, w2[kk], a2);
            }
        }
        __syncthreads();
        if (role == 2) {
            float hv[4];
            #pragma unroll
            for (int jj = 0; jj < 4; ++jj) {
                int rr = (rb + jj) * 17 + cv;
                float gr = ldsAcc[pr][0][rr];
                float gz = ldsAcc[pr][1][rr];
                float gn = ldsAcc[pr][2][rr];
                float r = sigf(gr + a0[jj] + bCr);
                float z = sigf(gz + a1[jj] + bCz);
                float n = tanhf(gn + bIn + r * (a2[jj] + bHn));
                hv[jj] = (1.0f - z) * n + z * hold[jj];
                hold[jj] = hv[jj];
            }
            STORE_TILE(h1buf[t & 1], hv[0], hv[1], hv[2], hv[3]);
            sigS<FAST>(fD1 + slot, t + 1);
            if (is_fc) {
                waitN<FAST, 32>(fD1, t + 1);
                if constexpr (FAST) l1inv();
                const _Float16* hb = h1buf[t & 1] + rgbase;
                #pragma unroll 1
                for (int r2 = 0; r2 < 16; ++r2) {
                    const _Float16* hp8 = hb + (lane >> 1) * 256 + r2 * 16 + (lane & 1) * 8;
                    half8 hv8 = gld16h<FAST>(hp8);
                    float pa = 0.f;
                    #pragma unroll
                    for (int e = 0; e < 8; ++e) pa += (float)hv8[e] * fw[e];
                    #pragma unroll
                    for (int m = 1; m < 64; m <<= 1) pa += __shfl_xor(pa, m);
                    if (lane == 0) {
                        int b = row0 + r2;
                        float yv2 = pa + fb;
                        gst4<FAST>(p.ybuf + b, yv2);
                        p.out[(size_t)b * OUTL + t] = yv2;
                    }
                }
                sigS<FAST>(fY, t + 1);
            }
        }
    }
#undef STORE_TILE
#undef LDS_A
}

__global__ __launch_bounds__(384, 1) void gru_all(
    const float* x,
    const float* ewih0, const float* ewhh0, const float* ebih0, const float* ebhh0,
    const float* ewih1, const float* ewhh1, const float* ebih1, const float* ebhh1,
    const float* lng,   const float* lnb,
    const float* dwih0, const float* dwhh0, const float* dbih0, const float* dbhh0,
    const float* dwih1, const float* dwhh1, const float* dbih1, const float* dbhh1,
    const float* fcw,   const float* fcb,
    float* out,
    _Float16* h0a, _Float16* h0b, _Float16* h1a, _Float16* h1b,
    float* hT0, float* hT1, float* ybuf, int* flags)
{
    __shared__ _Float16 ldsAB[16384];
    __shared__ float    ldsAcc[2][3][272];
    __shared__ _Float16 ldsOut[4][256];

    P p{x, ewih0, ewhh0, ebih0, ebhh0, ewih1, ewhh1, ebih1, ebhh1,
        lng, lnb, dwih0, dwhh0, dbih0, dbhh0, dwih1, dwhh1, dbih1, dbhh1,
        fcw, fcb, out, h0a, h0b, h1a, h1b, hT0, hT1, ybuf, flags};

    const int tid  = threadIdx.x;
    const int lane = tid & 63;
    const int rg   = blockIdx.x & 15, hp = blockIdx.x >> 4;

    // ---- runtime XCD-uniformity gate (agent-scope, r5-proven prims only) ----
    int* xt = flags + 6 * 16 * 32 + rg * 16;
    int xcc = 0;
    asm volatile("s_getreg_b32 %0, hwreg(HW_REG_XCC_ID)" : "=s"(xcc));
    if (tid == 0) a_sti(xt + hp, xcc + 1);
    bool fast;
    {
        int* pp = xt + (lane & 15);
        int v;
        while (true) {
            v = a_ldi(pp);
            if (__all(v >= 1)) break;
            __builtin_amdgcn_s_sleep(1);
        }
        int v0 = __shfl(v, 0);
        fast = __all(v == v0);
    }
    asm volatile("" ::: "memory");

    if (fast) gru_body<true>(p, ldsAB, ldsAcc, ldsOut);
    else      gru_body<false>(p, ldsAB, ldsAcc, ldsOut);
}

extern "C" void kernel_launch(void* const* d_in, const int* in_sizes, int n_in,
                              void* d_out, int out_size, void* d_ws, size_t ws_size,
                              hipStream_t stream)
{
    (void)in_sizes; (void)n_in; (void)out_size; (void)ws_size;
    char* ws = (char*)d_ws;
    size_t off = 0;
    auto alloc = [&](size_t bytes) -> void* {
        void* pv = ws + off;
        off += (bytes + 255) & ~(size_t)255;
        return pv;
    };

    // [flags(+xcd table)][h0a][h0b][h1a][h1b] zeroed each call; [hT0][hT1][ybuf]
    int* flags = (int*)alloc((6 * 16 * 32 + 16 * 16) * sizeof(int));
    const size_t HB = (size_t)Bsz * Hdim;
    _Float16* h0a = (_Float16*)alloc(HB * 2);
    _Float16* h0b = (_Float16*)alloc(HB * 2);
    _Float16* h1a = (_Float16*)alloc(HB * 2);
    _Float16* h1b = (_Float16*)alloc(HB * 2);
    size_t zbytes = off;
    float* hT0  = (float*)alloc(HB * 4);
    float* hT1  = (float*)alloc(HB * 4);
    float* ybuf = (float*)alloc(Bsz * 4);

    hipMemsetAsync(d_ws, 0, zbytes, stream);

    gru_all<<<256, 384, 0, stream>>>(
        (const float*)d_in[0],
        (const float*)d_in[1],  (const float*)d_in[2],
        (const float*)d_in[3],  (const float*)d_in[4],
        (const float*)d_in[5],  (const float*)d_in[6],
        (const float*)d_in[7],  (const float*)d_in[8],
        (const float*)d_in[9],  (const float*)d_in[10],
        (const float*)d_in[11], (const float*)d_in[12],
        (const float*)d_in[13], (const float*)d_in[14],
        (const float*)d_in[15], (const float*)d_in[16],
        (const float*)d_in[17], (const float*)d_in[18],
        (const float*)d_in[19], (const float*)d_in[20],
        (float*)d_out, h0a, h0b, h1a, h1b, hT0, hT1, ybuf, flags);
}

// Round 11
// 5228.008 us; speedup vs baseline: 6.1691x; 1.0643x over previous
//
#include <hip/hip_runtime.h>
#include <math.h>

// Seq2SeqGRU persistent kernel. B=256, T=512, H=512, OUT=10.
// 256 WGs x 384 threads. WG = (rg = blockIdx&15, hp = blockIdx>>4); all cross-WG
// traffic is rg-internal and XCD-local (XCC_ID gated, r10-proven).
// r11: FAST-path cross-WG STORES are atomic-exchange (global_atomic_swap[_x2],
// no sc bits) -> executed AT the XCD L2, line ALLOCATED there. r10 showed plain
// stores stream to MALL (no-write-allocate): FETCH/WRITE ~= h-size per step.
// Consumer loads stay plain after buffer_inv sc0 (L1-only inv) -> L2 hits.
// Flags: L2 atomic leg at slot, sc1 fabric leg at slot+32 (separate line,
// hang-proof progress guarantee). SLOW fallback = r7's all-sc1 scheme.

#define Hdim 512
#define Bsz  256
#define Tlen 512
#define OUTL 10

typedef _Float16 half8 __attribute__((ext_vector_type(8)));
typedef float    f32x4 __attribute__((ext_vector_type(4)));
typedef unsigned long long u64;

__device__ __forceinline__ f32x4 mfma16(half8 a, half8 b, f32x4 c) {
    return __builtin_amdgcn_mfma_f32_16x16x32_f16(a, b, c, 0, 0, 0);
}
__device__ __forceinline__ float sigf(float v) { return 1.0f / (1.0f + __expf(-v)); }
__device__ __forceinline__ half8 h8(u64 lo, u64 hi) {
    union { u64 u[2]; half8 h; } t; t.u[0] = lo; t.u[1] = hi; return t.h;
}

// ---- agent-scope relaxed prims (sc1; r5-r7 proven, cross-XCD safe) ----
__device__ __forceinline__ u64 a_ld8(const void* p) {
    return __hip_atomic_load((const u64*)p, __ATOMIC_RELAXED, __HIP_MEMORY_SCOPE_AGENT); }
__device__ __forceinline__ float a_ld4(const void* p) {
    return __hip_atomic_load((const float*)p, __ATOMIC_RELAXED, __HIP_MEMORY_SCOPE_AGENT); }
__device__ __forceinline__ int a_ldi(const int* p) {
    return __hip_atomic_load(p, __ATOMIC_RELAXED, __HIP_MEMORY_SCOPE_AGENT); }
__device__ __forceinline__ void a_st8(void* p, u64 v) {
    __hip_atomic_store((u64*)p, v, __ATOMIC_RELAXED, __HIP_MEMORY_SCOPE_AGENT); }
__device__ __forceinline__ void a_st4(void* p, float v) {
    __hip_atomic_store((float*)p, v, __ATOMIC_RELAXED, __HIP_MEMORY_SCOPE_AGENT); }
__device__ __forceinline__ void a_st2(void* p, unsigned short v) {
    __hip_atomic_store((unsigned short*)p, v, __ATOMIC_RELAXED, __HIP_MEMORY_SCOPE_AGENT); }
__device__ __forceinline__ void a_sti(int* p, int v) {
    __hip_atomic_store(p, v, __ATOMIC_RELAXED, __HIP_MEMORY_SCOPE_AGENT); }

// ---- L2-allocating stores: atomic exchange, workgroup scope -> no sc bits,
// executed in the local TCC (L2), line allocated+dirty there. ----
__device__ __forceinline__ void l2st8(void* p, u64 v) {
    __hip_atomic_exchange((u64*)p, v, __ATOMIC_RELAXED, __HIP_MEMORY_SCOPE_WORKGROUP);
}
__device__ __forceinline__ void l2st4f(float* p, float v) {
    __hip_atomic_exchange(p, v, __ATOMIC_RELAXED, __HIP_MEMORY_SCOPE_WORKGROUP);
}
__device__ __forceinline__ void l2sti(int* p, int v) {
    __hip_atomic_exchange(p, v, __ATOMIC_RELAXED, __HIP_MEMORY_SCOPE_WORKGROUP);
}

// L1-ONLY invalidate (sc0). Does NOT touch L2 (sc1 variant = r9's 5x regression).
__device__ __forceinline__ void l1inv() {
    asm volatile("buffer_inv sc0" ::: "memory");
}

// ---- templated data accessors: FAST = L2-local, SLOW = sc1 agent ----
template<bool FAST> __device__ __forceinline__ float gld4(const float* p) {
    if constexpr (FAST) return *p; else return a_ld4(p);
}
template<bool FAST> __device__ __forceinline__ void gst4(float* p, float v) {
    if constexpr (FAST) l2st4f(p, v); else a_st4(p, v);
}
template<bool FAST> __device__ __forceinline__ void gst8(_Float16* p, u64 v) {
    if constexpr (FAST) l2st8(p, v); else a_st8(p, v);
}
template<bool FAST> __device__ __forceinline__ half8 gld16h(const _Float16* p) {
    if constexpr (FAST) return *(const half8*)p;
    else return h8(a_ld8(p), a_ld8(p + 4));
}

// signal: drain stores/atomics (vmcnt covers both), then flag legs.
// FAST: L2 atomic leg at slot + sc1 leg at slot+32 (separate 128B line).
template<bool FAST>
__device__ __forceinline__ void sigS(int* slot, int val) {
    asm volatile("s_waitcnt vmcnt(0)" ::: "memory");
    if ((threadIdx.x & 63) == 0) {
        if constexpr (FAST) { l2sti(slot, val); a_sti(slot + 32, val); }
        else a_sti(slot, val);
    }
}
// wait: FAST = l1inv + plain probes (hit L2 line allocated by producer's atomic),
// sc1 progress leg on the separate line every 16 probes; SLOW = r7 poll.
template<bool FAST, int NS>
__device__ __forceinline__ void waitN(int* base, int target) {
    if (target <= 0) return;
    int idx = (threadIdx.x & 63) % NS;
    int* p  = base + idx;
    while (true) {
        if constexpr (FAST) {
            bool ok = false;
            #pragma unroll 1
            for (int k = 0; k < 16; ++k) {
                l1inv();
                int v = *(volatile int*)p;
                if (__all(v >= target)) { ok = true; break; }
            }
            if (ok) break;
            int v2 = a_ldi(base + 32 + idx);      // fabric leg (progress guarantee)
            if (__all(v2 >= target)) break;
        } else {
            int v2 = a_ldi(p);
            if (__all(v2 >= target)) break;
        }
        __builtin_amdgcn_s_sleep(1);
    }
    asm volatile("" ::: "memory");
}

__device__ __forceinline__ half8 ld_cvt(const float* p) {
    float4 a = *(const float4*)p;
    float4 b = *(const float4*)(p + 4);
    half8 v;
    v[0]=(_Float16)a.x; v[1]=(_Float16)a.y; v[2]=(_Float16)a.z; v[3]=(_Float16)a.w;
    v[4]=(_Float16)b.x; v[5]=(_Float16)b.y; v[6]=(_Float16)b.z; v[7]=(_Float16)b.w;
    return v;
}

// Stage both contiguous 16KB rg blocks -> LDS (linear, tile-major layout).
template<bool FAST>
__device__ __forceinline__ void stage2(_Float16* ldsAB, const _Float16* sA,
                                       const _Float16* sB, int tid) {
    if constexpr (FAST) {
        #pragma unroll
        for (int u = 0; u < 3; ++u) {
            int c = tid + u * 384;
            if (c < 1024) {
                half8 vb = *(const half8*)(sB + c * 8);
                half8 va = *(const half8*)(sA + c * 8);
                *(half8*)&ldsAB[8192 + c * 8] = vb;
                *(half8*)&ldsAB[c * 8] = va;
            }
        }
    } else {
        u64 tvB[6], tvA[6];
        #pragma unroll
        for (int u = 0; u < 6; ++u) {
            int c = tid + u * 384;
            if (c < 2048) { tvB[u] = a_ld8(sB + c * 4); tvA[u] = a_ld8(sA + c * 4); }
        }
        #pragma unroll
        for (int u = 0; u < 6; ++u) {
            int c = tid + u * 384;
            if (c < 2048) {
                *(u64*)&ldsAB[8192 + c * 4] = tvB[u];
                *(u64*)&ldsAB[c * 4] = tvA[u];
            }
        }
    }
}

// LayerNorm of 16 rows (one wave). hT f32 in/out; dst16rg tile-major f16 copy.
template<bool FAST>
__device__ void ln_rows(float* hT, _Float16* dst16rg, const float* gam, const float* bet,
                        int row0, int lane) {
    #pragma unroll 1
    for (int r = 0; r < 16; ++r) {
        float* pr_ = hT + (size_t)(row0 + r) * Hdim;
        float v[8];
        if constexpr (FAST) {
            float4 v0 = *(const float4*)(pr_ + lane * 8);
            float4 v1 = *(const float4*)(pr_ + lane * 8 + 4);
            v[0]=v0.x; v[1]=v0.y; v[2]=v0.z; v[3]=v0.w;
            v[4]=v1.x; v[5]=v1.y; v[6]=v1.z; v[7]=v1.w;
        } else {
            #pragma unroll
            for (int e = 0; e < 4; ++e) {
                union { u64 u; float f[2]; } c;
                c.u = a_ld8(pr_ + lane * 8 + e * 2);
                v[2*e] = c.f[0]; v[2*e+1] = c.f[1];
            }
        }
        float s = 0.f, sq = 0.f;
        #pragma unroll
        for (int e = 0; e < 8; ++e) { s += v[e]; sq += v[e] * v[e]; }
        #pragma unroll
        for (int m = 1; m < 64; m <<= 1) { s += __shfl_xor(s, m); sq += __shfl_xor(sq, m); }
        float mean = s * (1.0f / Hdim);
        float rstd = rsqrtf(sq * (1.0f / Hdim) - mean * mean + 1e-5f);
        float o[8];
        #pragma unroll
        for (int e = 0; e < 8; ++e)
            o[e] = (v[e] - mean) * rstd * gam[lane * 8 + e] + bet[lane * 8 + e];
        _Float16* d = dst16rg + (lane >> 1) * 256 + r * 16 + (lane & 1) * 8;
        if constexpr (FAST) {
            #pragma unroll
            for (int e2 = 0; e2 < 4; ++e2) {
                union { u64 u; float f[2]; } pk;
                pk.f[0] = o[2*e2]; pk.f[1] = o[2*e2+1];
                l2st8(pr_ + lane * 8 + 2 * e2, pk.u);
            }
            union { u64 u; _Float16 h[4]; } hk0, hk1;
            #pragma unroll
            for (int e = 0; e < 4; ++e) { hk0.h[e] = (_Float16)o[e]; hk1.h[e] = (_Float16)o[4+e]; }
            l2st8(d, hk0.u);
            l2st8(d + 4, hk1.u);
        } else {
            #pragma unroll
            for (int e = 0; e < 8; ++e) {
                a_st4(pr_ + lane * 8 + e, o[e]);
                a_st2(d + e, __builtin_bit_cast(unsigned short, (_Float16)o[e]));
            }
        }
    }
}

struct P {
    const float *x, *ewih0, *ewhh0, *ebih0, *ebhh0, *ewih1, *ewhh1, *ebih1, *ebhh1;
    const float *lng, *lnb, *dwih0, *dwhh0, *dbih0, *dbhh0, *dwih1, *dwhh1, *dbih1, *dbhh1;
    const float *fcw, *fcb;
    float* out;
    _Float16 *h0a, *h0b, *h1a, *h1b;
    float *hT0, *hT1, *ybuf;
    int* flags;
};

// flag layout: (kind*16+rg)*64 ints. [0,32) = L2 legs, [32,64) = sc1 legs.
#define FSTRIDE 64

template<bool FAST>
__device__ __forceinline__ void gru_body(const P& p, _Float16 (&ldsAB)[16384],
                                         float (&ldsAcc)[2][3][272], _Float16 (&ldsOut)[4][256])
{
    const int tid  = threadIdx.x;
    const int wid  = tid >> 6, lane = tid & 63;
    const int role = wid >> 1;              // 0=L0/dec0, 1=GI, 2=GH
    const int pr   = wid & 1;
    const int rg   = blockIdx.x & 15, hp = blockIdx.x >> 4;
    const int cv   = lane & 15, kg = lane >> 4;
    const int hs   = hp * 2 + pr;
    const int hid  = hs * 16 + cv;
    const int row0 = rg * 16;
    const int rb   = kg * 4;
    const int slot = hp * 2 + pr;
    const int ow   = (role == 0) ? pr : 2 + pr;
    const size_t rgbase = (size_t)rg * 32 * 256;

    int* f0  = p.flags + (0 * 16 + rg) * FSTRIDE;
    int* f1  = p.flags + (1 * 16 + rg) * FSTRIDE;
    int* fD0 = p.flags + (2 * 16 + rg) * FSTRIDE;
    int* fD1 = p.flags + (3 * 16 + rg) * FSTRIDE;
    int* fLN = p.flags + (4 * 16 + rg) * FSTRIDE;
    int* fY  = p.flags + (5 * 16 + rg) * FSTRIDE;

    _Float16* h0buf[2] = {p.h0a, p.h0b};
    _Float16* h1buf[2] = {p.h1a, p.h1b};

    // ---- encoder weights -> registers/AGPRs (plain cached loads, read-once) ----
    half8 w0[16], w1[16], w2[16];
    {
        const float* wsP = role == 0 ? p.ewhh0 : (role == 1 ? p.ewih1 : p.ewhh1);
        const float* b0 = wsP + (size_t)hid * Hdim + kg * 8;
        #pragma unroll
        for (int kk = 0; kk < 16; ++kk) {
            w0[kk] = ld_cvt(b0 + kk * 32);
            w1[kk] = ld_cvt(b0 + (size_t)512 * Hdim + kk * 32);
            w2[kk] = ld_cvt(b0 + (size_t)1024 * Hdim + kk * 32);
        }
    }
    float cw_r0 = 0, cw_r1 = 0, cw_z0 = 0, cw_z1 = 0, cw_n0 = 0, cw_n1 = 0;
    float bCr = 0, bCz = 0, bIn = 0, bHn = 0;
    if (role == 0) {
        cw_r0 = p.ewih0[hid * 2];          cw_r1 = p.ewih0[hid * 2 + 1];
        cw_z0 = p.ewih0[(512 + hid) * 2];  cw_z1 = p.ewih0[(512 + hid) * 2 + 1];
        cw_n0 = p.ewih0[(1024 + hid) * 2]; cw_n1 = p.ewih0[(1024 + hid) * 2 + 1];
        bCr = p.ebih0[hid] + p.ebhh0[hid];
        bCz = p.ebih0[512 + hid] + p.ebhh0[512 + hid];
        bIn = p.ebih0[1024 + hid]; bHn = p.ebhh0[1024 + hid];
    } else if (role == 2) {
        bCr = p.ebih1[hid] + p.ebhh1[hid];
        bCz = p.ebih1[512 + hid] + p.ebhh1[512 + hid];
        bIn = p.ebih1[1024 + hid]; bHn = p.ebhh1[1024 + hid];
    }
    float hold[4] = {0.f, 0.f, 0.f, 0.f};

#define LDS_A(BASE, KK) \
    (*(const half8*)&ldsAB[(BASE) + (2 * (KK) + (kg >> 1)) * 256 + cv * 16 + (kg & 1) * 8])
#define STORE_TILE(DSTBUF, HV0, HV1, HV2, HV3)                                   \
    do {                                                                         \
        ldsOut[ow][(rb + 0) * 16 + cv] = (_Float16)(HV0);                        \
        ldsOut[ow][(rb + 1) * 16 + cv] = (_Float16)(HV1);                        \
        ldsOut[ow][(rb + 2) * 16 + cv] = (_Float16)(HV2);                        \
        ldsOut[ow][(rb + 3) * 16 + cv] = (_Float16)(HV3);                        \
        u64 pk_ = *(const u64*)&ldsOut[ow][lane * 4];                            \
        gst8<FAST>((DSTBUF) + rgbase + (size_t)hs * 256 + lane * 4, pk_);        \
    } while (0)

    // ================= encoder: 513 iterations =================
    // iter i: layer0 step i (i<512), layer1 step i-1 (i>=1)
    for (int i = 0; i <= Tlen; ++i) {
        float2 xv[4];
        if (role == 0 && i < Tlen) {
            #pragma unroll
            for (int jj = 0; jj < 4; ++jj)
                xv[jj] = *(const float2*)(p.x + ((size_t)(row0 + rb + jj) * Tlen + i) * 2);
        }
        waitN<FAST, 32>(f1, i - 1);         // h1[i-2] complete
        waitN<FAST, 32>(f0, i);             // h0[i-1] complete
        if constexpr (FAST) l1inv();        // drop stale L1; L2 holds fresh lines
        stage2<FAST>(ldsAB, h0buf[(i - 1) & 1] + rgbase, h1buf[(i - 2) & 1] + rgbase, tid);
        __syncthreads();   // stage visible
        f32x4 a0 = {0,0,0,0}, a1 = {0,0,0,0}, a2 = {0,0,0,0};
        if (role == 2) {
            if (i >= 1) {
                #pragma unroll
                for (int kk = 0; kk < 16; ++kk) {
                    half8 a = LDS_A(8192, kk);
                    a0 = mfma16(a, w0[kk], a0);
                    a1 = mfma16(a, w1[kk], a1);
                    a2 = mfma16(a, w2[kk], a2);
                }
            }
        } else if (role == 0) {
            if (i < Tlen) {
                #pragma unroll
                for (int kk = 0; kk < 16; ++kk) {
                    half8 a = LDS_A(0, kk);
                    a0 = mfma16(a, w0[kk], a0);
                    a1 = mfma16(a, w1[kk], a1);
                    a2 = mfma16(a, w2[kk], a2);
                }
                float hv[4];
                #pragma unroll
                for (int jj = 0; jj < 4; ++jj) {
                    int b = row0 + rb + jj;
                    float x0 = xv[jj].x, x1 = xv[jj].y;
                    float r = sigf(x0 * cw_r0 + x1 * cw_r1 + a0[jj] + bCr);
                    float z = sigf(x0 * cw_z0 + x1 * cw_z1 + a1[jj] + bCz);
                    float n = tanhf(x0 * cw_n0 + x1 * cw_n1 + bIn + r * (a2[jj] + bHn));
                    hv[jj] = (1.0f - z) * n + z * hold[jj];
                    hold[jj] = hv[jj];
                    if (i == Tlen - 1) gst4<FAST>(p.hT0 + (size_t)b * Hdim + hid, hv[jj]);
                }
                STORE_TILE(h0buf[i & 1], hv[0], hv[1], hv[2], hv[3]);
                sigS<FAST>(f0 + slot, i + 1);
            }
        } else { // GI: gi = y0[i-1] @ wih1^T
            if (i >= 1) {
                #pragma unroll
                for (int kk = 0; kk < 16; ++kk) {
                    half8 a = LDS_A(0, kk);
                    a0 = mfma16(a, w0[kk], a0);
                    a1 = mfma16(a, w1[kk], a1);
                    a2 = mfma16(a, w2[kk], a2);
                }
                #pragma unroll
                for (int jj = 0; jj < 4; ++jj) {
                    int rr = (rb + jj) * 17 + cv;
                    ldsAcc[pr][0][rr] = a0[jj];
                    ldsAcc[pr][1][rr] = a1[jj];
                    ldsAcc[pr][2][rr] = a2[jj];
                }
            }
        }
        __syncthreads();   // ldsAcc visible
        if (role == 2 && i >= 1) {
            float hv[4];
            #pragma unroll
            for (int jj = 0; jj < 4; ++jj) {
                int b = row0 + rb + jj;
                int rr = (rb + jj) * 17 + cv;
                float gr = ldsAcc[pr][0][rr];
                float gz = ldsAcc[pr][1][rr];
                float gn = ldsAcc[pr][2][rr];
                float r = sigf(gr + a0[jj] + bCr);
                float z = sigf(gz + a1[jj] + bCz);
                float n = tanhf(gn + bIn + r * (a2[jj] + bHn));
                hv[jj] = (1.0f - z) * n + z * hold[jj];
                hold[jj] = hv[jj];
                if (i == Tlen) gst4<FAST>(p.hT1 + (size_t)b * Hdim + hid, hv[jj]);
            }
            STORE_TILE(h1buf[(i - 1) & 1], hv[0], hv[1], hv[2], hv[3]);
            sigS<FAST>(f1 + slot, i);      // h1[i-1] done
        }
    }

    // ================= LayerNorm =================
    if (hp == 0 && wid == 0) {
        waitN<FAST, 32>(f0, Tlen);
        waitN<FAST, 32>(f1, Tlen);
        if constexpr (FAST) l1inv();
        ln_rows<FAST>(p.hT0, h0buf[1] + rgbase, p.lng, p.lnb, row0, lane);
        if (lane < 16) {
            int b = row0 + lane;
            gst4<FAST>(p.ybuf + b, p.x[((size_t)b * Tlen + (Tlen - 1)) * 2 + 1]);
        }
        sigS<FAST>(fLN + 0, 1);
    }
    if (hp == 0 && wid == 4) {
        waitN<FAST, 32>(f1, Tlen);
        if constexpr (FAST) l1inv();
        ln_rows<FAST>(p.hT1, h1buf[1] + rgbase, p.lng, p.lnb, row0, lane);
        sigS<FAST>(fLN + 1, 1);
    }

    // ---- decoder weights ----
    {
        const float* wsP = role == 0 ? p.dwhh0 : (role == 1 ? p.dwih1 : p.dwhh1);
        const float* b0 = wsP + (size_t)hid * Hdim + kg * 8;
        #pragma unroll
        for (int kk = 0; kk < 16; ++kk) {
            w0[kk] = ld_cvt(b0 + kk * 32);
            w1[kk] = ld_cvt(b0 + (size_t)512 * Hdim + kk * 32);
            w2[kk] = ld_cvt(b0 + (size_t)1024 * Hdim + kk * 32);
        }
    }
    if (role == 0) {
        cw_r0 = p.dwih0[hid]; cw_z0 = p.dwih0[512 + hid]; cw_n0 = p.dwih0[1024 + hid];
        bCr = p.dbih0[hid] + p.dbhh0[hid];
        bCz = p.dbih0[512 + hid] + p.dbhh0[512 + hid];
        bIn = p.dbih0[1024 + hid]; bHn = p.dbhh0[1024 + hid];
    } else if (role == 2) {
        bCr = p.dbih1[hid] + p.dbhh1[hid];
        bCz = p.dbih1[512 + hid] + p.dbhh1[512 + hid];
        bIn = p.dbih1[1024 + hid]; bHn = p.dbhh1[1024 + hid];
    }
    float fw[8] = {0,0,0,0,0,0,0,0};
    float fb = 0.f;
    const bool is_fc = (hp == 0 && wid == 4);
    if (is_fc) {
        #pragma unroll
        for (int e = 0; e < 8; ++e) fw[e] = p.fcw[lane * 8 + e];
        fb = p.fcb[0];
    }
    waitN<FAST, 2>(fLN, 1);
    if constexpr (FAST) l1inv();
    if (role == 0 || role == 2) {
        const float* hTsrc = (role == 0) ? p.hT0 : p.hT1;
        #pragma unroll
        for (int jj = 0; jj < 4; ++jj)
            hold[jj] = gld4<FAST>(hTsrc + (size_t)(row0 + rb + jj) * Hdim + hid);
    }

    // ================= decoder: 10 steps =================
    for (int t = 0; t < OUTL; ++t) {
        waitN<FAST, 32>(fD1, t);
        waitN<FAST, 32>(fD0, t);
        if (role == 0) waitN<FAST, 1>(fY, t);
        if constexpr (FAST) l1inv();
        stage2<FAST>(ldsAB, h0buf[(t - 1) & 1] + rgbase, h1buf[(t - 1) & 1] + rgbase, tid);
        __syncthreads();
        f32x4 a0 = {0,0,0,0}, a1 = {0,0,0,0}, a2 = {0,0,0,0};
        if (role == 0) {
            float yvv[4];
            #pragma unroll
            for (int jj = 0; jj < 4; ++jj) yvv[jj] = gld4<FAST>(p.ybuf + row0 + rb + jj);
            #pragma unroll
            for (int kk = 0; kk < 16; ++kk) {
                half8 a = LDS_A(0, kk);
                a0 = mfma16(a, w0[kk], a0);
                a1 = mfma16(a, w1[kk], a1);
                a2 = mfma16(a, w2[kk], a2);
            }
            float hv[4];
            #pragma unroll
            for (int jj = 0; jj < 4; ++jj) {
                float yv = yvv[jj];
                float r = sigf(yv * cw_r0 + a0[jj] + bCr);
                float z = sigf(yv * cw_z0 + a1[jj] + bCz);
                float n = tanhf(yv * cw_n0 + bIn + r * (a2[jj] + bHn));
                hv[jj] = (1.0f - z) * n + z * hold[jj];
                hold[jj] = hv[jj];
            }
            STORE_TILE(h0buf[t & 1], hv[0], hv[1], hv[2], hv[3]);
            sigS<FAST>(fD0 + slot, t + 1);
        } else if (role == 1) {
            waitN<FAST, 32>(fD0, t + 1);    // fresh h0dec[t]
            if constexpr (FAST) l1inv();
            const _Float16* agb = h0buf[t & 1] + rgbase;
            #pragma unroll
            for (int kk = 0; kk < 16; ++kk) {
                const _Float16* pa = agb + (2 * kk + (kg >> 1)) * 256 + cv * 16 + (kg & 1) * 8;
                half8 q = gld16h<FAST>(pa);
                a0 = mfma16(q, w0[kk], a0);
                a1 = mfma16(q, w1[kk], a1);
                a2 = mfma16(q, w2[kk], a2);
            }
            #pragma unroll
            for (int jj = 0; jj < 4; ++jj) {
                int rr = (rb + jj) * 17 + cv;
                ldsAcc[pr][0][rr] = a0[jj];
                ldsAcc[pr][1][rr] = a1[jj];
                ldsAcc[pr][2][rr] = a2[jj];
            }
        } else {
            #pragma unroll
            for (int kk = 0; kk < 16; ++kk) {
                half8 a = LDS_A(8192, kk);
                a0 = mfma16(a, w0[kk], a0);
                a1 = mfma16(a, w1[kk], a1);
                a2 = mfma16(a, w2[kk], a2);
            }
        }
        __syncthreads();
        if (role == 2) {
            float hv[4];
            #pragma unroll
            for (int jj = 0; jj < 4; ++jj) {
                int rr = (rb + jj) * 17 + cv;
                float gr = ldsAcc[pr][0][rr];
                float gz = ldsAcc[pr][1][rr];
                float gn = ldsAcc[pr][2][rr];
                float r = sigf(gr + a0[jj] + bCr);
                float z = sigf(gz + a1[jj] + bCz);
                float n = tanhf(gn + bIn + r * (a2[jj] + bHn));
                hv[jj] = (1.0f - z) * n + z * hold[jj];
                hold[jj] = hv[jj];
            }
            STORE_TILE(h1buf[t & 1], hv[0], hv[1], hv[2], hv[3]);
            sigS<FAST>(fD1 + slot, t + 1);
            if (is_fc) {
                waitN<FAST, 32>(fD1, t + 1);
                if constexpr (FAST) l1inv();
                const _Float16* hb = h1buf[t & 1] + rgbase;
                #pragma unroll 1
                for (int r2 = 0; r2 < 16; ++r2) {
                    const _Float16* hp8 = hb + (lane >> 1) * 256 + r2 * 16 + (lane & 1) * 8;
                    half8 hv8 = gld16h<FAST>(hp8);
                    float pa = 0.f;
                    #pragma unroll
                    for (int e = 0; e < 8; ++e) pa += (float)hv8[e] * fw[e];
                    #pragma unroll
                    for (int m = 1; m < 64; m <<= 1) pa += __shfl_xor(pa, m);
                    if (lane == 0) {
                        int b = row0 + r2;
                        float yv2 = pa + fb;
                        gst4<FAST>(p.ybuf + b, yv2);
                        p.out[(size_t)b * OUTL + t] = yv2;
                    }
                }
                sigS<FAST>(fY, t + 1);
            }
        }
    }
#undef STORE_TILE
#undef LDS_A
}

__global__ __launch_bounds__(384, 1) void gru_all(
    const float* x,
    const float* ewih0, const float* ewhh0, const float* ebih0, const float* ebhh0,
    const float* ewih1, const float* ewhh1, const float* ebih1, const float* ebhh1,
    const float* lng,   const float* lnb,
    const float* dwih0, const float* dwhh0, const float* dbih0, const float* dbhh0,
    const float* dwih1, const float* dwhh1, const float* dbih1, const float* dbhh1,
    const float* fcw,   const float* fcb,
    float* out,
    _Float16* h0a, _Float16* h0b, _Float16* h1a, _Float16* h1b,
    float* hT0, float* hT1, float* ybuf, int* flags)
{
    __shared__ _Float16 ldsAB[16384];
    __shared__ float    ldsAcc[2][3][272];
    __shared__ _Float16 ldsOut[4][256];

    P p{x, ewih0, ewhh0, ebih0, ebhh0, ewih1, ewhh1, ebih1, ebhh1,
        lng, lnb, dwih0, dwhh0, dbih0, dbhh0, dwih1, dwhh1, dbih1, dbhh1,
        fcw, fcb, out, h0a, h0b, h1a, h1b, hT0, hT1, ybuf, flags};

    const int tid  = threadIdx.x;
    const int lane = tid & 63;
    const int rg   = blockIdx.x & 15, hp = blockIdx.x >> 4;

    // ---- runtime XCD-uniformity gate (agent-scope, r5-proven prims only) ----
    int* xt = flags + 6 * 16 * FSTRIDE + rg * 16;
    int xcc = 0;
    asm volatile("s_getreg_b32 %0, hwreg(HW_REG_XCC_ID)" : "=s"(xcc));
    if (tid == 0) a_sti(xt + hp, xcc + 1);
    bool fast;
    {
        int* pp = xt + (lane & 15);
        int v;
        while (true) {
            v = a_ldi(pp);
            if (__all(v >= 1)) break;
            __builtin_amdgcn_s_sleep(1);
        }
        int v0 = __shfl(v, 0);
        fast = __all(v == v0);
    }
    asm volatile("" ::: "memory");

    if (fast) gru_body<true>(p, ldsAB, ldsAcc, ldsOut);
    else      gru_body<false>(p, ldsAB, ldsAcc, ldsOut);
}

extern "C" void kernel_launch(void* const* d_in, const int* in_sizes, int n_in,
                              void* d_out, int out_size, void* d_ws, size_t ws_size,
                              hipStream_t stream)
{
    (void)in_sizes; (void)n_in; (void)out_size; (void)ws_size;
    char* ws = (char*)d_ws;
    size_t off = 0;
    auto alloc = [&](size_t bytes) -> void* {
        void* pv = ws + off;
        off += (bytes + 255) & ~(size_t)255;
        return pv;
    };

    // [flags(+xcd table)][h0a][h0b][h1a][h1b] zeroed each call; [hT0][hT1][ybuf]
    int* flags = (int*)alloc((6 * 16 * 64 + 16 * 16) * sizeof(int));
    const size_t HB = (size_t)Bsz * Hdim;
    _Float16* h0a = (_Float16*)alloc(HB * 2);
    _Float16* h0b = (_Float16*)alloc(HB * 2);
    _Float16* h1a = (_Float16*)alloc(HB * 2);
    _Float16* h1b = (_Float16*)alloc(HB * 2);
    size_t zbytes = off;
    float* hT0  = (float*)alloc(HB * 4);
    float* hT1  = (float*)alloc(HB * 4);
    float* ybuf = (float*)alloc(Bsz * 4);

    hipMemsetAsync(d_ws, 0, zbytes, stream);

    gru_all<<<256, 384, 0, stream>>>(
        (const float*)d_in[0],
        (const float*)d_in[1],  (const float*)d_in[2],
        (const float*)d_in[3],  (const float*)d_in[4],
        (const float*)d_in[5],  (const float*)d_in[6],
        (const float*)d_in[7],  (const float*)d_in[8],
        (const float*)d_in[9],  (const float*)d_in[10],
        (const float*)d_in[11], (const float*)d_in[12],
        (const float*)d_in[13], (const float*)d_in[14],
        (const float*)d_in[15], (const float*)d_in[16],
        (const float*)d_in[17], (const float*)d_in[18],
        (const float*)d_in[19], (const float*)d_in[20],
        (float*)d_out, h0a, h0b, h1a, h1b, hT0, hT1, ybuf, flags);
}

// Round 12
// 4239.936 us; speedup vs baseline: 7.6068x; 1.2330x over previous
//
#include <hip/hip_runtime.h>
#include <math.h>

// Seq2SeqGRU persistent kernel, layer-split pools. B=256, T=512, H=512, OUT=10.
// 192 WGs x 512 thr. rg = blockIdx&15 (16 batch rows), g = blockIdx>>4 in [0,12):
//   g in [0,4)  -> POOL A (layer0/dec0): 8 waves, slice hs = g*8+wid in [0,32)
//   g in [4,12) -> POOL B (layer1/dec1): waves 0-3 gi, 4-7 gh; hs = (g-4)*4 + (wid&3)
// Pool A's recurrence loop = ONE wait + ONE 16KB stage + ONE barrier + drain
// (r11's coupled design dragged 2 waits/2 barriers/2 drains through the chain).
// Layer1 consumes y0 via ring-4 h0 buffer (lag-3 back-pressure, never binds).
// All cross-WG traffic: relaxed agent-scope sc1 atomics (r7-proven, dispatch-safe).

#define Hdim 512
#define Bsz  256
#define Tlen 512
#define OUTL 10

typedef _Float16 half8 __attribute__((ext_vector_type(8)));
typedef float    f32x4 __attribute__((ext_vector_type(4)));
typedef unsigned long long u64;

__device__ __forceinline__ f32x4 mfma16(half8 a, half8 b, f32x4 c) {
    return __builtin_amdgcn_mfma_f32_16x16x32_f16(a, b, c, 0, 0, 0);
}
__device__ __forceinline__ float sigf(float v) { return 1.0f / (1.0f + __expf(-v)); }
__device__ __forceinline__ half8 h8(u64 lo, u64 hi) {
    union { u64 u[2]; half8 h; } t; t.u[0] = lo; t.u[1] = hi; return t.h;
}

// ---- relaxed agent-scope (sc1) prims — r5-r7 proven, any-dispatch-safe ----
__device__ __forceinline__ u64 a_ld8(const void* p) {
    return __hip_atomic_load((const u64*)p, __ATOMIC_RELAXED, __HIP_MEMORY_SCOPE_AGENT); }
__device__ __forceinline__ float a_ld4(const void* p) {
    return __hip_atomic_load((const float*)p, __ATOMIC_RELAXED, __HIP_MEMORY_SCOPE_AGENT); }
__device__ __forceinline__ int a_ldi(const int* p) {
    return __hip_atomic_load(p, __ATOMIC_RELAXED, __HIP_MEMORY_SCOPE_AGENT); }
__device__ __forceinline__ void a_st8(void* p, u64 v) {
    __hip_atomic_store((u64*)p, v, __ATOMIC_RELAXED, __HIP_MEMORY_SCOPE_AGENT); }
__device__ __forceinline__ void a_st4(void* p, float v) {
    __hip_atomic_store((float*)p, v, __ATOMIC_RELAXED, __HIP_MEMORY_SCOPE_AGENT); }
__device__ __forceinline__ void a_st2(void* p, unsigned short v) {
    __hip_atomic_store((unsigned short*)p, v, __ATOMIC_RELAXED, __HIP_MEMORY_SCOPE_AGENT); }
__device__ __forceinline__ void a_sti(int* p, int v) {
    __hip_atomic_store(p, v, __ATOMIC_RELAXED, __HIP_MEMORY_SCOPE_AGENT); }

// signal: drain outstanding sc1 stores, then store val to own slot.
__device__ __forceinline__ void sigS(int* slot, int val) {
    asm volatile("s_waitcnt vmcnt(0)" ::: "memory");
    if ((threadIdx.x & 63) == 0) a_sti(slot, val);
}
// wait: all NS slots >= target (one wave-wide poll load per iter).
template <int NS>
__device__ __forceinline__ void waitS(int* base, int target) {
    if (target <= 0) return;
    int* p = base + ((threadIdx.x & 63) % NS);
    while (true) {
        int v = a_ldi(p);
        if (__all(v >= target)) break;
        __builtin_amdgcn_s_sleep(1);
    }
    asm volatile("" ::: "memory");
}

__device__ __forceinline__ half8 ld_cvt(const float* p) {
    float4 a = *(const float4*)p;
    float4 b = *(const float4*)(p + 4);
    half8 v;
    v[0]=(_Float16)a.x; v[1]=(_Float16)a.y; v[2]=(_Float16)a.z; v[3]=(_Float16)a.w;
    v[4]=(_Float16)b.x; v[5]=(_Float16)b.y; v[6]=(_Float16)b.z; v[7]=(_Float16)b.w;
    return v;
}

// LayerNorm of 16 rows (one wave). hT f32 in/out (row-major); dst16rg = tile-major
// f16 copy at the rg block base.
__device__ void ln_rows(float* hT, _Float16* dst16rg, const float* gam, const float* bet,
                        int row0, int lane) {
    #pragma unroll 1
    for (int r = 0; r < 16; ++r) {
        float* pr_ = hT + (size_t)(row0 + r) * Hdim;
        float v[8];
        #pragma unroll
        for (int e = 0; e < 4; ++e) {
            union { u64 u; float f[2]; } c;
            c.u = a_ld8(pr_ + lane * 8 + e * 2);
            v[2*e] = c.f[0]; v[2*e+1] = c.f[1];
        }
        float s = 0.f, sq = 0.f;
        #pragma unroll
        for (int e = 0; e < 8; ++e) { s += v[e]; sq += v[e] * v[e]; }
        #pragma unroll
        for (int m = 1; m < 64; m <<= 1) { s += __shfl_xor(s, m); sq += __shfl_xor(sq, m); }
        float mean = s * (1.0f / Hdim);
        float rstd = rsqrtf(sq * (1.0f / Hdim) - mean * mean + 1e-5f);
        _Float16* d = dst16rg + (lane >> 1) * 256 + r * 16 + (lane & 1) * 8;
        #pragma unroll
        for (int e = 0; e < 8; ++e) {
            int k = lane * 8 + e;
            float o = (v[e] - mean) * rstd * gam[k] + bet[k];
            a_st4(pr_ + k, o);
            a_st2(d + e, __builtin_bit_cast(unsigned short, (_Float16)o));
        }
    }
}

// ws layout (256B-aligned constants, mirrored host-side)
#define OFF_FLAGS 0
#define SZ_FLAGS  (6 * 16 * 32 * 4)            // f0,f1,fD0,fD1,fLN,fY
#define H16B      262144                        // one f16 h buffer (256 rows x 512)
#define OFF_H0R   (OFF_FLAGS + SZ_FLAGS)        // ring-4
#define OFF_H1R   (OFF_H0R + 4 * H16B)          // ring-2
#define ZBYTES    (OFF_H1R + 2 * H16B)          // memset range
#define OFF_H0D   ZBYTES                        // dec rings (2)
#define OFF_H1D   (OFF_H0D + 2 * H16B)
#define OFF_HT0   (OFF_H1D + 2 * H16B)          // f32 512KB
#define OFF_HT1   (OFF_HT0 + 524288)
#define OFF_YB    (OFF_HT1 + 524288)
#define WS_NEED   (OFF_YB + 1024)

__global__ __launch_bounds__(512, 1) void gru_all(
    const float* __restrict__ x,
    const float* __restrict__ ewih0, const float* __restrict__ ewhh0,
    const float* __restrict__ ebih0, const float* __restrict__ ebhh0,
    const float* __restrict__ ewih1, const float* __restrict__ ewhh1,
    const float* __restrict__ ebih1, const float* __restrict__ ebhh1,
    const float* __restrict__ lng,   const float* __restrict__ lnb,
    const float* __restrict__ dwih0, const float* __restrict__ dwhh0,
    const float* __restrict__ dbih0, const float* __restrict__ dbhh0,
    const float* __restrict__ dwih1, const float* __restrict__ dwhh1,
    const float* __restrict__ dbih1, const float* __restrict__ dbhh1,
    const float* __restrict__ fcw,   const float* __restrict__ fcb,
    float* __restrict__ out, char* __restrict__ ws)
{
    __shared__ _Float16 ldsY[8192];         // 16KB: h0/y0 (A stage / B y0)
    __shared__ _Float16 ldsH[8192];         // 16KB: h1 (B only)
    __shared__ float    ldsAcc[4][3][272];  // gi->gh handoff (B)
    __shared__ _Float16 ldsOut[8][256];     // per-wave store repack

    const int tid  = threadIdx.x;
    const int wid  = tid >> 6, lane = tid & 63;
    const int rg   = blockIdx.x & 15;
    const int g    = blockIdx.x >> 4;       // [0,12)
    const bool poolA = (g < 4);
    const int cv   = lane & 15, kg = lane >> 4;
    const int row0 = rg * 16;
    const int rb   = kg * 4;
    const size_t rgbase = (size_t)rg * 32 * 256;

    int* flags = (int*)(ws + OFF_FLAGS);
    int* f0  = flags + (0 * 16 + rg) * 32;
    int* f1  = flags + (1 * 16 + rg) * 32;
    int* fD0 = flags + (2 * 16 + rg) * 32;
    int* fD1 = flags + (3 * 16 + rg) * 32;
    int* fLN = flags + (4 * 16 + rg) * 32;
    int* fY  = flags + (5 * 16 + rg) * 32;
    _Float16* h0r[4] = {(_Float16*)(ws+OFF_H0R), (_Float16*)(ws+OFF_H0R+H16B),
                        (_Float16*)(ws+OFF_H0R+2*H16B), (_Float16*)(ws+OFF_H0R+3*H16B)};
    _Float16* h1r[2] = {(_Float16*)(ws+OFF_H1R), (_Float16*)(ws+OFF_H1R+H16B)};
    _Float16* h0d[2] = {(_Float16*)(ws+OFF_H0D), (_Float16*)(ws+OFF_H0D+H16B)};
    _Float16* h1d[2] = {(_Float16*)(ws+OFF_H1D), (_Float16*)(ws+OFF_H1D+H16B)};
    float* hT0  = (float*)(ws + OFF_HT0);
    float* hT1  = (float*)(ws + OFF_HT1);
    float* ybuf = (float*)(ws + OFF_YB);

    // slice / role
    const bool gi = (!poolA) && (wid < 4);
    const int  hs = poolA ? (g * 8 + wid) : ((g - 4) * 4 + (wid & 3));
    const int  hid = hs * 16 + cv;
    const int  ow = poolA ? wid : (wid & 3);

#define LDS_A(ARR, KK) \
    (*(const half8*)&(ARR)[(2 * (KK) + (kg >> 1)) * 256 + cv * 16 + (kg & 1) * 8])
#define STORE_TILE(DST, HV0, HV1, HV2, HV3)                                      \
    do {                                                                         \
        ldsOut[ow][(rb + 0) * 16 + cv] = (_Float16)(HV0);                        \
        ldsOut[ow][(rb + 1) * 16 + cv] = (_Float16)(HV1);                        \
        ldsOut[ow][(rb + 2) * 16 + cv] = (_Float16)(HV2);                        \
        ldsOut[ow][(rb + 3) * 16 + cv] = (_Float16)(HV3);                        \
        u64 pk_ = *(const u64*)&ldsOut[ow][lane * 4];                            \
        a_st8((DST) + rgbase + (size_t)hs * 256 + lane * 4, pk_);                \
    } while (0)

    // ---- encoder weights -> registers ----
    half8 w0[16], w1[16], w2[16];
    {
        const float* wsP = poolA ? ewhh0 : (gi ? ewih1 : ewhh1);
        const float* b0 = wsP + (size_t)hid * Hdim + kg * 8;
        #pragma unroll
        for (int kk = 0; kk < 16; ++kk) {
            w0[kk] = ld_cvt(b0 + kk * 32);
            w1[kk] = ld_cvt(b0 + (size_t)512 * Hdim + kk * 32);
            w2[kk] = ld_cvt(b0 + (size_t)1024 * Hdim + kk * 32);
        }
    }
    float cw_r0 = 0, cw_r1 = 0, cw_z0 = 0, cw_z1 = 0, cw_n0 = 0, cw_n1 = 0;
    float bCr = 0, bCz = 0, bIn = 0, bHn = 0;
    if (poolA) {
        cw_r0 = ewih0[hid * 2];          cw_r1 = ewih0[hid * 2 + 1];
        cw_z0 = ewih0[(512 + hid) * 2];  cw_z1 = ewih0[(512 + hid) * 2 + 1];
        cw_n0 = ewih0[(1024 + hid) * 2]; cw_n1 = ewih0[(1024 + hid) * 2 + 1];
        bCr = ebih0[hid] + ebhh0[hid];
        bCz = ebih0[512 + hid] + ebhh0[512 + hid];
        bIn = ebih0[1024 + hid]; bHn = ebhh0[1024 + hid];
    } else if (!gi) {
        bCr = ebih1[hid] + ebhh1[hid];
        bCz = ebih1[512 + hid] + ebhh1[512 + hid];
        bIn = ebih1[1024 + hid]; bHn = ebhh1[1024 + hid];
    }
    float hold[4] = {0.f, 0.f, 0.f, 0.f};

    // ================= encoder =================
    if (poolA) {
        for (int i = 0; i < Tlen; ++i) {
            float2 xv[4];
            #pragma unroll
            for (int jj = 0; jj < 4; ++jj)
                xv[jj] = *(const float2*)(x + ((size_t)(row0 + rb + jj) * Tlen + i) * 2);
            waitS<32>(f1, i - 3);            // ring-4 back-pressure (rarely binds)
            waitS<32>(f0, i);                // h0[i-1] ready
            {
                const _Float16* s = h0r[(i + 3) & 3] + rgbase;
                u64 tv[4];
                #pragma unroll
                for (int u = 0; u < 4; ++u) tv[u] = a_ld8(s + (tid + u * 512) * 4);
                #pragma unroll
                for (int u = 0; u < 4; ++u) *(u64*)&ldsY[(tid + u * 512) * 4] = tv[u];
            }
            __syncthreads();
            f32x4 a0 = {0,0,0,0}, a1 = {0,0,0,0}, a2 = {0,0,0,0};
            #pragma unroll
            for (int kk = 0; kk < 16; ++kk) {
                half8 a = LDS_A(ldsY, kk);
                a0 = mfma16(a, w0[kk], a0);
                a1 = mfma16(a, w1[kk], a1);
                a2 = mfma16(a, w2[kk], a2);
            }
            float hv[4];
            #pragma unroll
            for (int jj = 0; jj < 4; ++jj) {
                int b = row0 + rb + jj;
                float x0 = xv[jj].x, x1 = xv[jj].y;
                float r = sigf(x0 * cw_r0 + x1 * cw_r1 + a0[jj] + bCr);
                float z = sigf(x0 * cw_z0 + x1 * cw_z1 + a1[jj] + bCz);
                float n = tanhf(x0 * cw_n0 + x1 * cw_n1 + bIn + r * (a2[jj] + bHn));
                hv[jj] = (1.0f - z) * n + z * hold[jj];
                hold[jj] = hv[jj];
                if (i == Tlen - 1) a_st4(hT0 + (size_t)b * Hdim + hid, hv[jj]);
            }
            STORE_TILE(h0r[i & 3], hv[0], hv[1], hv[2], hv[3]);
            sigS(f0 + hs, i + 1);
            // no trailing barrier: next stage-write gated by waitS(f0,i+1),
            // and every wave signals only after its ldsY reads completed.
        }
    } else {
        for (int u = 0; u < Tlen; ++u) {
            waitS<32>(f1, u);                // h1[u-1] ready
            waitS<32>(f0, u + 1);            // y0[u] ready
            {
                const _Float16* sy = h0r[u & 3] + rgbase;
                const _Float16* sh = h1r[(u + 1) & 1] + rgbase;
                u64 ty[4], th[4];
                #pragma unroll
                for (int v = 0; v < 4; ++v) {
                    ty[v] = a_ld8(sy + (tid + v * 512) * 4);
                    th[v] = a_ld8(sh + (tid + v * 512) * 4);
                }
                #pragma unroll
                for (int v = 0; v < 4; ++v) {
                    *(u64*)&ldsY[(tid + v * 512) * 4] = ty[v];
                    *(u64*)&ldsH[(tid + v * 512) * 4] = th[v];
                }
            }
            __syncthreads();
            f32x4 a0 = {0,0,0,0}, a1 = {0,0,0,0}, a2 = {0,0,0,0};
            if (gi) {
                #pragma unroll
                for (int kk = 0; kk < 16; ++kk) {
                    half8 a = LDS_A(ldsY, kk);
                    a0 = mfma16(a, w0[kk], a0);
                    a1 = mfma16(a, w1[kk], a1);
                    a2 = mfma16(a, w2[kk], a2);
                }
                #pragma unroll
                for (int jj = 0; jj < 4; ++jj) {
                    int rr = (rb + jj) * 17 + cv;
                    ldsAcc[wid][0][rr] = a0[jj];
                    ldsAcc[wid][1][rr] = a1[jj];
                    ldsAcc[wid][2][rr] = a2[jj];
                }
            } else {
                #pragma unroll
                for (int kk = 0; kk < 16; ++kk) {
                    half8 a = LDS_A(ldsH, kk);
                    a0 = mfma16(a, w0[kk], a0);
                    a1 = mfma16(a, w1[kk], a1);
                    a2 = mfma16(a, w2[kk], a2);
                }
            }
            __syncthreads();
            if (!gi) {
                float hv[4];
                #pragma unroll
                for (int jj = 0; jj < 4; ++jj) {
                    int b = row0 + rb + jj;
                    int rr = (rb + jj) * 17 + cv;
                    float gr = ldsAcc[wid & 3][0][rr];
                    float gz = ldsAcc[wid & 3][1][rr];
                    float gn = ldsAcc[wid & 3][2][rr];
                    float r = sigf(gr + a0[jj] + bCr);
                    float z = sigf(gz + a1[jj] + bCz);
                    float n = tanhf(gn + bIn + r * (a2[jj] + bHn));
                    hv[jj] = (1.0f - z) * n + z * hold[jj];
                    hold[jj] = hv[jj];
                    if (u == Tlen - 1) a_st4(hT1 + (size_t)b * Hdim + hid, hv[jj]);
                }
                STORE_TILE(h1r[u & 1], hv[0], hv[1], hv[2], hv[3]);
                sigS(f1 + hs, u + 1);
            }
        }
    }

    // ================= LayerNorm =================
    if (poolA && g == 0 && wid == 0) {
        waitS<32>(f0, Tlen);
        ln_rows(hT0, h0d[1] + rgbase, lng, lnb, row0, lane);
        if (lane < 16) {
            int b = row0 + lane;
            a_st4(ybuf + b, x[((size_t)b * Tlen + (Tlen - 1)) * 2 + 1]);
        }
        sigS(fLN + 0, 1);
    }
    if (!poolA && g == 4 && wid == 0) {
        waitS<32>(f1, Tlen);
        ln_rows(hT1, h1d[1] + rgbase, lng, lnb, row0, lane);
        sigS(fLN + 1, 1);
    }

    // ---- decoder weights ----
    {
        const float* wsP = poolA ? dwhh0 : (gi ? dwih1 : dwhh1);
        const float* b0 = wsP + (size_t)hid * Hdim + kg * 8;
        #pragma unroll
        for (int kk = 0; kk < 16; ++kk) {
            w0[kk] = ld_cvt(b0 + kk * 32);
            w1[kk] = ld_cvt(b0 + (size_t)512 * Hdim + kk * 32);
            w2[kk] = ld_cvt(b0 + (size_t)1024 * Hdim + kk * 32);
        }
    }
    if (poolA) {
        cw_r0 = dwih0[hid]; cw_z0 = dwih0[512 + hid]; cw_n0 = dwih0[1024 + hid];
        bCr = dbih0[hid] + dbhh0[hid];
        bCz = dbih0[512 + hid] + dbhh0[512 + hid];
        bIn = dbih0[1024 + hid]; bHn = dbhh0[1024 + hid];
    } else if (!gi) {
        bCr = dbih1[hid] + dbhh1[hid];
        bCz = dbih1[512 + hid] + dbhh1[512 + hid];
        bIn = dbih1[1024 + hid]; bHn = dbhh1[1024 + hid];
    }
    float fw[8] = {0,0,0,0,0,0,0,0};
    float fb = 0.f;
    const bool is_fc = (!poolA) && (g == 4) && (wid == 7);
    if (is_fc) {
        #pragma unroll
        for (int e = 0; e < 8; ++e) fw[e] = fcw[lane * 8 + e];
        fb = fcb[0];
    }
    waitS<2>(fLN, 1);
    if (poolA) {
        #pragma unroll
        for (int jj = 0; jj < 4; ++jj)
            hold[jj] = a_ld4(hT0 + (size_t)(row0 + rb + jj) * Hdim + hid);
    } else if (!gi) {
        #pragma unroll
        for (int jj = 0; jj < 4; ++jj)
            hold[jj] = a_ld4(hT1 + (size_t)(row0 + rb + jj) * Hdim + hid);
    }

    // ================= decoder: 10 steps =================
    if (poolA) {
        for (int t = 0; t < OUTL; ++t) {
            waitS<32>(fD0, t);
            waitS<1>(fY, t);
            {
                const _Float16* s = h0d[(t + 1) & 1] + rgbase;
                u64 tv[4];
                #pragma unroll
                for (int u = 0; u < 4; ++u) tv[u] = a_ld8(s + (tid + u * 512) * 4);
                #pragma unroll
                for (int u = 0; u < 4; ++u) *(u64*)&ldsY[(tid + u * 512) * 4] = tv[u];
            }
            __syncthreads();
            float yvv[4];
            #pragma unroll
            for (int jj = 0; jj < 4; ++jj) yvv[jj] = a_ld4(ybuf + row0 + rb + jj);
            f32x4 a0 = {0,0,0,0}, a1 = {0,0,0,0}, a2 = {0,0,0,0};
            #pragma unroll
            for (int kk = 0; kk < 16; ++kk) {
                half8 a = LDS_A(ldsY, kk);
                a0 = mfma16(a, w0[kk], a0);
                a1 = mfma16(a, w1[kk], a1);
                a2 = mfma16(a, w2[kk], a2);
            }
            float hv[4];
            #pragma unroll
            for (int jj = 0; jj < 4; ++jj) {
                float yv = yvv[jj];
                float r = sigf(yv * cw_r0 + a0[jj] + bCr);
                float z = sigf(yv * cw_z0 + a1[jj] + bCz);
                float n = tanhf(yv * cw_n0 + bIn + r * (a2[jj] + bHn));
                hv[jj] = (1.0f - z) * n + z * hold[jj];
                hold[jj] = hv[jj];
            }
            STORE_TILE(h0d[t & 1], hv[0], hv[1], hv[2], hv[3]);
            sigS(fD0 + hs, t + 1);
        }
    } else {
        for (int t = 0; t < OUTL; ++t) {
            waitS<32>(fD1, t);
            {
                const _Float16* s = h1d[(t + 1) & 1] + rgbase;
                u64 tv[4];
                #pragma unroll
                for (int u = 0; u < 4; ++u) tv[u] = a_ld8(s + (tid + u * 512) * 4);
                #pragma unroll
                for (int u = 0; u < 4; ++u) *(u64*)&ldsH[(tid + u * 512) * 4] = tv[u];
            }
            __syncthreads();
            f32x4 a0 = {0,0,0,0}, a1 = {0,0,0,0}, a2 = {0,0,0,0};
            if (gi) {
                waitS<32>(fD0, t + 1);       // fresh h0dec[t]
                const _Float16* agb = h0d[t & 1] + rgbase;
                #pragma unroll
                for (int kk = 0; kk < 16; ++kk) {
                    const _Float16* pa = agb + (2 * kk + (kg >> 1)) * 256
                                       + cv * 16 + (kg & 1) * 8;
                    half8 q = h8(a_ld8(pa), a_ld8(pa + 4));
                    a0 = mfma16(q, w0[kk], a0);
                    a1 = mfma16(q, w1[kk], a1);
                    a2 = mfma16(q, w2[kk], a2);
                }
                #pragma unroll
                for (int jj = 0; jj < 4; ++jj) {
                    int rr = (rb + jj) * 17 + cv;
                    ldsAcc[wid][0][rr] = a0[jj];
                    ldsAcc[wid][1][rr] = a1[jj];
                    ldsAcc[wid][2][rr] = a2[jj];
                }
            } else {
                #pragma unroll
                for (int kk = 0; kk < 16; ++kk) {
                    half8 a = LDS_A(ldsH, kk);
                    a0 = mfma16(a, w0[kk], a0);
                    a1 = mfma16(a, w1[kk], a1);
                    a2 = mfma16(a, w2[kk], a2);
                }
            }
            __syncthreads();
            if (!gi) {
                float hv[4];
                #pragma unroll
                for (int jj = 0; jj < 4; ++jj) {
                    int rr = (rb + jj) * 17 + cv;
                    float gr = ldsAcc[wid & 3][0][rr];
                    float gz = ldsAcc[wid & 3][1][rr];
                    float gn = ldsAcc[wid & 3][2][rr];
                    float r = sigf(gr + a0[jj] + bCr);
                    float z = sigf(gz + a1[jj] + bCz);
                    float n = tanhf(gn + bIn + r * (a2[jj] + bHn));
                    hv[jj] = (1.0f - z) * n + z * hold[jj];
                    hold[jj] = hv[jj];
                }
                STORE_TILE(h1d[t & 1], hv[0], hv[1], hv[2], hv[3]);
                sigS(fD1 + hs, t + 1);
                if (is_fc) {
                    waitS<32>(fD1, t + 1);
                    const _Float16* hb = h1d[t & 1] + rgbase;
                    #pragma unroll 1
                    for (int r2 = 0; r2 < 16; ++r2) {
                        const _Float16* hp8 = hb + (lane >> 1) * 256 + r2 * 16 + (lane & 1) * 8;
                        half8 hv8 = h8(a_ld8(hp8), a_ld8(hp8 + 4));
                        float pa = 0.f;
                        #pragma unroll
                        for (int e = 0; e < 8; ++e) pa += (float)hv8[e] * fw[e];
                        #pragma unroll
                        for (int m = 1; m < 64; m <<= 1) pa += __shfl_xor(pa, m);
                        if (lane == 0) {
                            int b = row0 + r2;
                            float yv2 = pa + fb;
                            a_st4(ybuf + b, yv2);
                            out[(size_t)b * OUTL + t] = yv2;
                        }
                    }
                    sigS(fY, t + 1);
                }
            }
        }
    }
#undef STORE_TILE
#undef LDS_A
}

extern "C" void kernel_launch(void* const* d_in, const int* in_sizes, int n_in,
                              void* d_out, int out_size, void* d_ws, size_t ws_size,
                              hipStream_t stream)
{
    (void)in_sizes; (void)n_in; (void)out_size; (void)ws_size;
    hipMemsetAsync(d_ws, 0, ZBYTES, stream);
    gru_all<<<192, 512, 0, stream>>>(
        (const float*)d_in[0],
        (const float*)d_in[1],  (const float*)d_in[2],
        (const float*)d_in[3],  (const float*)d_in[4],
        (const float*)d_in[5],  (const float*)d_in[6],
        (const float*)d_in[7],  (const float*)d_in[8],
        (const float*)d_in[9],  (const float*)d_in[10],
        (const float*)d_in[11], (const float*)d_in[12],
        (const float*)d_in[13], (const float*)d_in[14],
        (const float*)d_in[15], (const float*)d_in[16],
        (const float*)d_in[17], (const float*)d_in[18],
        (const float*)d_in[19], (const float*)d_in[20],
        (float*)d_out, (char*)d_ws);
}

// Round 13
// 4202.446 us; speedup vs baseline: 7.6746x; 1.0089x over previous
//
#include <hip/hip_runtime.h>
#include <math.h>

// Seq2SeqGRU persistent kernel, layer-split pools + SEQLOCK exchange.
// B=256, T=512, H=512, OUT=10. 192 WGs x 512 thr; rg=blockIdx&15, g=blockIdx>>4:
//   g<4: POOL A (layer0): 8 waves, slice hs=g*8+wid.
//   g>=4: POOL B (layer1): waves 0-3 gi, 4-7 gh; hs=(g-4)*4+(wid&3).
// r13: encoder h exchange = seqlock units. Each 8B unit = [4B payload | 4B seq],
// stored with ONE 8B relaxed-agent atomic (ISA-atomic, no tearing). Consumers
// spin directly on the units: seq==step <=> data valid. Removes the per-step
// producer vmcnt-drain + flag store + flag detect (~2 fabric RTTs of r12's chain).
// Ring-4 on h0/h1; pool A throttled by cons0 (B's consumed counter); pool B
// lockstep +-1 via its own spin => no overwrite-before-read (audited).
// Decoder/LN keep r12's proven flag scheme.

#define Hdim 512
#define Bsz  256
#define Tlen 512
#define OUTL 10

typedef _Float16 half8 __attribute__((ext_vector_type(8)));
typedef float    f32x4 __attribute__((ext_vector_type(4)));
typedef unsigned long long u64;
typedef unsigned int uint;

__device__ __forceinline__ f32x4 mfma16(half8 a, half8 b, f32x4 c) {
    return __builtin_amdgcn_mfma_f32_16x16x32_f16(a, b, c, 0, 0, 0);
}
__device__ __forceinline__ float sigf(float v) { return 1.0f / (1.0f + __expf(-v)); }
__device__ __forceinline__ half8 h8(u64 lo, u64 hi) {
    union { u64 u[2]; half8 h; } t; t.u[0] = lo; t.u[1] = hi; return t.h;
}

// ---- relaxed agent-scope (sc1) prims — r5-r12 proven ----
__device__ __forceinline__ u64 a_ld8(const void* p) {
    return __hip_atomic_load((const u64*)p, __ATOMIC_RELAXED, __HIP_MEMORY_SCOPE_AGENT); }
__device__ __forceinline__ float a_ld4(const void* p) {
    return __hip_atomic_load((const float*)p, __ATOMIC_RELAXED, __HIP_MEMORY_SCOPE_AGENT); }
__device__ __forceinline__ int a_ldi(const int* p) {
    return __hip_atomic_load(p, __ATOMIC_RELAXED, __HIP_MEMORY_SCOPE_AGENT); }
__device__ __forceinline__ void a_st8(void* p, u64 v) {
    __hip_atomic_store((u64*)p, v, __ATOMIC_RELAXED, __HIP_MEMORY_SCOPE_AGENT); }
__device__ __forceinline__ void a_st4(void* p, float v) {
    __hip_atomic_store((float*)p, v, __ATOMIC_RELAXED, __HIP_MEMORY_SCOPE_AGENT); }
__device__ __forceinline__ void a_st2(void* p, unsigned short v) {
    __hip_atomic_store((unsigned short*)p, v, __ATOMIC_RELAXED, __HIP_MEMORY_SCOPE_AGENT); }
__device__ __forceinline__ void a_sti(int* p, int v) {
    __hip_atomic_store(p, v, __ATOMIC_RELAXED, __HIP_MEMORY_SCOPE_AGENT); }

__device__ __forceinline__ void sigS(int* slot, int val) {
    asm volatile("s_waitcnt vmcnt(0)" ::: "memory");
    if ((threadIdx.x & 63) == 0) a_sti(slot, val);
}
template <int NS>
__device__ __forceinline__ void waitS(int* base, int target) {
    if (target <= 0) return;
    int* p = base + ((threadIdx.x & 63) % NS);
    while (true) {
        int v = a_ldi(p);
        if (__all(v >= target)) break;
        __builtin_amdgcn_s_sleep(1);
    }
    asm volatile("" ::: "memory");
}

__device__ __forceinline__ half8 ld_cvt(const float* p) {
    float4 a = *(const float4*)p;
    float4 b = *(const float4*)(p + 4);
    half8 v;
    v[0]=(_Float16)a.x; v[1]=(_Float16)a.y; v[2]=(_Float16)a.z; v[3]=(_Float16)a.w;
    v[4]=(_Float16)b.x; v[5]=(_Float16)b.y; v[6]=(_Float16)b.z; v[7]=(_Float16)b.w;
    return v;
}

// LayerNorm of 16 rows (one wave). hT f32 in/out; dst16rg tile-major f16 copy.
__device__ void ln_rows(float* hT, _Float16* dst16rg, const float* gam, const float* bet,
                        int row0, int lane) {
    #pragma unroll 1
    for (int r = 0; r < 16; ++r) {
        float* pr_ = hT + (size_t)(row0 + r) * Hdim;
        float v[8];
        #pragma unroll
        for (int e = 0; e < 4; ++e) {
            union { u64 u; float f[2]; } c;
            c.u = a_ld8(pr_ + lane * 8 + e * 2);
            v[2*e] = c.f[0]; v[2*e+1] = c.f[1];
        }
        float s = 0.f, sq = 0.f;
        #pragma unroll
        for (int e = 0; e < 8; ++e) { s += v[e]; sq += v[e] * v[e]; }
        #pragma unroll
        for (int m = 1; m < 64; m <<= 1) { s += __shfl_xor(s, m); sq += __shfl_xor(sq, m); }
        float mean = s * (1.0f / Hdim);
        float rstd = rsqrtf(sq * (1.0f / Hdim) - mean * mean + 1e-5f);
        _Float16* d = dst16rg + (lane >> 1) * 256 + r * 16 + (lane & 1) * 8;
        #pragma unroll
        for (int e = 0; e < 8; ++e) {
            int k = lane * 8 + e;
            float o = (v[e] - mean) * rstd * gam[k] + bet[k];
            a_st4(pr_ + k, o);
            a_st2(d + e, __builtin_bit_cast(unsigned short, (_Float16)o));
        }
    }
}

// ws layout
#define OFF_FLAGS 0
#define SZ_FLAGS  (8 * 16 * 32 * 4)     // kinds: 0=fEnc0 1=fEnc1 2=fD0 3=fD1 4=fLN 5=fY 6=cons0
#define RUNITS    4096                   // 8B units per rg per buffer (16KB payload)
#define RSLOTSZ   (16 * RUNITS * 8)      // one ring slot = 512KB
#define OFF_H0R   (OFF_FLAGS + SZ_FLAGS)
#define OFF_H1R   (OFF_H0R + 4 * RSLOTSZ)
#define ZBYTES    (OFF_H1R + 4 * RSLOTSZ)
#define H16B      262144
#define OFF_H0D   ZBYTES
#define OFF_H1D   (OFF_H0D + 2 * H16B)
#define OFF_HT0   (OFF_H1D + 2 * H16B)
#define OFF_HT1   (OFF_HT0 + 524288)
#define OFF_YB    (OFF_HT1 + 524288)

__global__ __launch_bounds__(512, 1) void gru_all(
    const float* __restrict__ x,
    const float* __restrict__ ewih0, const float* __restrict__ ewhh0,
    const float* __restrict__ ebih0, const float* __restrict__ ebhh0,
    const float* __restrict__ ewih1, const float* __restrict__ ewhh1,
    const float* __restrict__ ebih1, const float* __restrict__ ebhh1,
    const float* __restrict__ lng,   const float* __restrict__ lnb,
    const float* __restrict__ dwih0, const float* __restrict__ dwhh0,
    const float* __restrict__ dbih0, const float* __restrict__ dbhh0,
    const float* __restrict__ dwih1, const float* __restrict__ dwhh1,
    const float* __restrict__ dbih1, const float* __restrict__ dbhh1,
    const float* __restrict__ fcw,   const float* __restrict__ fcb,
    float* __restrict__ out, char* __restrict__ ws)
{
    __shared__ _Float16 ldsY[8192];
    __shared__ _Float16 ldsH[8192];
    __shared__ float    ldsAcc[4][3][272];
    __shared__ _Float16 ldsOut[8][256];

    const int tid  = threadIdx.x;
    const int wid  = tid >> 6, lane = tid & 63;
    const int rg   = blockIdx.x & 15;
    const int g    = blockIdx.x >> 4;
    const bool poolA = (g < 4);
    const int cv   = lane & 15, kg = lane >> 4;
    const int row0 = rg * 16;
    const int rb   = kg * 4;
    const size_t rgbase = (size_t)rg * 32 * 256;     // decoder buffers (f16 elems)

    int* flags = (int*)(ws + OFF_FLAGS);
    int* fEnc0 = flags + (0 * 16 + rg) * 32;
    int* fEnc1 = flags + (1 * 16 + rg) * 32;
    int* fD0   = flags + (2 * 16 + rg) * 32;
    int* fD1   = flags + (3 * 16 + rg) * 32;
    int* fLN   = flags + (4 * 16 + rg) * 32;
    int* fY    = flags + (5 * 16 + rg) * 32;
    int* cons0 = flags + (6 * 16 + rg) * 32;

    u64* r0rg = (u64*)(ws + OFF_H0R) + (size_t)rg * RUNITS;   // + slot*16*RUNITS
    u64* r1rg = (u64*)(ws + OFF_H1R) + (size_t)rg * RUNITS;
    _Float16* h0d[2] = {(_Float16*)(ws+OFF_H0D), (_Float16*)(ws+OFF_H0D+H16B)};
    _Float16* h1d[2] = {(_Float16*)(ws+OFF_H1D), (_Float16*)(ws+OFF_H1D+H16B)};
    float* hT0  = (float*)(ws + OFF_HT0);
    float* hT1  = (float*)(ws + OFF_HT1);
    float* ybuf = (float*)(ws + OFF_YB);

    const bool gi = (!poolA) && (wid < 4);
    const int  hs = poolA ? (g * 8 + wid) : ((g - 4) * 4 + (wid & 3));
    const int  hid = hs * 16 + cv;
    const int  ow = poolA ? wid : (wid & 3);

#define LDS_A(ARR, KK) \
    (*(const half8*)&(ARR)[(2 * (KK) + (kg >> 1)) * 256 + cv * 16 + (kg & 1) * 8])
    // seqlock tile store: repack via ldsOut, then 2x 8B atomic [payload|seq].
#define STORE_SEQ(DSTSLOT, SEQ, HV0, HV1, HV2, HV3)                              \
    do {                                                                         \
        ldsOut[ow][(rb + 0) * 16 + cv] = (_Float16)(HV0);                        \
        ldsOut[ow][(rb + 1) * 16 + cv] = (_Float16)(HV1);                        \
        ldsOut[ow][(rb + 2) * 16 + cv] = (_Float16)(HV2);                        \
        ldsOut[ow][(rb + 3) * 16 + cv] = (_Float16)(HV3);                        \
        uint d0_ = ((uint*)&ldsOut[ow][0])[lane * 2];                            \
        uint d1_ = ((uint*)&ldsOut[ow][0])[lane * 2 + 1];                        \
        u64* dst_ = (DSTSLOT) + hs * 128 + lane * 2;                             \
        u64 sq_ = ((u64)(uint)(SEQ)) << 32;                                      \
        a_st8(dst_,     sq_ | d0_);                                              \
        a_st8(dst_ + 1, sq_ | d1_);                                              \
    } while (0)
    // r12-style plain tile store (decoder, flag-guarded)
#define STORE_TILE(DST, HV0, HV1, HV2, HV3)                                      \
    do {                                                                         \
        ldsOut[ow][(rb + 0) * 16 + cv] = (_Float16)(HV0);                        \
        ldsOut[ow][(rb + 1) * 16 + cv] = (_Float16)(HV1);                        \
        ldsOut[ow][(rb + 2) * 16 + cv] = (_Float16)(HV2);                        \
        ldsOut[ow][(rb + 3) * 16 + cv] = (_Float16)(HV3);                        \
        u64 pk_ = *(const u64*)&ldsOut[ow][lane * 4];                            \
        a_st8((DST) + rgbase + (size_t)hs * 256 + lane * 4, pk_);                \
    } while (0)

    // ---- encoder weights -> registers ----
    half8 w0[16], w1[16], w2[16];
    {
        const float* wsP = poolA ? ewhh0 : (gi ? ewih1 : ewhh1);
        const float* b0 = wsP + (size_t)hid * Hdim + kg * 8;
        #pragma unroll
        for (int kk = 0; kk < 16; ++kk) {
            w0[kk] = ld_cvt(b0 + kk * 32);
            w1[kk] = ld_cvt(b0 + (size_t)512 * Hdim + kk * 32);
            w2[kk] = ld_cvt(b0 + (size_t)1024 * Hdim + kk * 32);
        }
    }
    float cw_r0 = 0, cw_r1 = 0, cw_z0 = 0, cw_z1 = 0, cw_n0 = 0, cw_n1 = 0;
    float bCr = 0, bCz = 0, bIn = 0, bHn = 0;
    if (poolA) {
        cw_r0 = ewih0[hid * 2];          cw_r1 = ewih0[hid * 2 + 1];
        cw_z0 = ewih0[(512 + hid) * 2];  cw_z1 = ewih0[(512 + hid) * 2 + 1];
        cw_n0 = ewih0[(1024 + hid) * 2]; cw_n1 = ewih0[(1024 + hid) * 2 + 1];
        bCr = ebih0[hid] + ebhh0[hid];
        bCz = ebih0[512 + hid] + ebhh0[512 + hid];
        bIn = ebih0[1024 + hid]; bHn = ebhh0[1024 + hid];
    } else if (!gi) {
        bCr = ebih1[hid] + ebhh1[hid];
        bCz = ebih1[512 + hid] + ebhh1[512 + hid];
        bIn = ebih1[1024 + hid]; bHn = ebhh1[1024 + hid];
    }
    float hold[4] = {0.f, 0.f, 0.f, 0.f};

    // ================= encoder =================
    if (poolA) {
        for (int i = 0; i < Tlen; ++i) {
            float2 xv[4];
            #pragma unroll
            for (int jj = 0; jj < 4; ++jj)
                xv[jj] = *(const float2*)(x + ((size_t)(row0 + rb + jj) * Tlen + i) * 2);
            // spin-stage h0[i-1]: slot (i-1)&3, seq == i  (i=0: zeros, seq 0)
            const u64* src = r0rg + (size_t)((i + 3) & 3) * (16 * RUNITS);
            const uint tgt = (uint)i;
            u64 v[8];
            #pragma unroll
            for (int k = 0; k < 8; ++k) v[k] = a_ld8(src + tid + k * 512);
            while (true) {
                bool all = true;
                #pragma unroll
                for (int k = 0; k < 8; ++k)
                    if ((uint)(v[k] >> 32) != tgt) { all = false; v[k] = a_ld8(src + tid + k * 512); }
                if (all) break;
                __builtin_amdgcn_s_sleep(1);
            }
            #pragma unroll
            for (int k = 0; k < 8; ++k) ((uint*)ldsY)[tid + k * 512] = (uint)v[k];
            __syncthreads();
            f32x4 a0 = {0,0,0,0}, a1 = {0,0,0,0}, a2 = {0,0,0,0};
            #pragma unroll
            for (int kk = 0; kk < 16; ++kk) {
                half8 a = LDS_A(ldsY, kk);
                a0 = mfma16(a, w0[kk], a0);
                a1 = mfma16(a, w1[kk], a1);
                a2 = mfma16(a, w2[kk], a2);
            }
            float hv[4];
            #pragma unroll
            for (int jj = 0; jj < 4; ++jj) {
                int b = row0 + rb + jj;
                float x0 = xv[jj].x, x1 = xv[jj].y;
                float r = sigf(x0 * cw_r0 + x1 * cw_r1 + a0[jj] + bCr);
                float z = sigf(x0 * cw_z0 + x1 * cw_z1 + a1[jj] + bCz);
                float n = tanhf(x0 * cw_n0 + x1 * cw_n1 + bIn + r * (a2[jj] + bHn));
                hv[jj] = (1.0f - z) * n + z * hold[jj];
                hold[jj] = hv[jj];
                if (i == Tlen - 1) a_st4(hT0 + (size_t)b * Hdim + hid, hv[jj]);
            }
            waitS<8>(cons0, i - 3);      // y0 slot i&3 overwrite: B consumed y0[i-4]
            STORE_SEQ(r0rg + (size_t)(i & 3) * (16 * RUNITS), i + 1,
                      hv[0], hv[1], hv[2], hv[3]);
            // no drain, no flag: consumers spin on seq itself.
        }
        sigS(fEnc0 + hs, 1);             // drains final hT0 + h stores
    } else {
        for (int u = 0; u < Tlen; ++u) {
            // spin-stage y0[u] (slot u&3, seq u+1) and h1[u-1] (slot (u-1)&3, seq u)
            const u64* sy = r0rg + (size_t)(u & 3) * (16 * RUNITS);
            const u64* sh = r1rg + (size_t)((u + 3) & 3) * (16 * RUNITS);
            const uint ty = (uint)(u + 1), th = (uint)u;
            u64 vy[8], vh[8];
            #pragma unroll
            for (int k = 0; k < 8; ++k) {
                vy[k] = a_ld8(sy + tid + k * 512);
                vh[k] = a_ld8(sh + tid + k * 512);
            }
            while (true) {
                bool all = true;
                #pragma unroll
                for (int k = 0; k < 8; ++k) {
                    if ((uint)(vy[k] >> 32) != ty) { all = false; vy[k] = a_ld8(sy + tid + k * 512); }
                    if ((uint)(vh[k] >> 32) != th) { all = false; vh[k] = a_ld8(sh + tid + k * 512); }
                }
                if (all) break;
                __builtin_amdgcn_s_sleep(1);
            }
            #pragma unroll
            for (int k = 0; k < 8; ++k) {
                ((uint*)ldsY)[tid + k * 512] = (uint)vy[k];
                ((uint*)ldsH)[tid + k * 512] = (uint)vh[k];
            }
            __syncthreads();
            if (tid == 0) a_sti(cons0 + (g - 4), u + 1);   // y0[u] consumed
            f32x4 a0 = {0,0,0,0}, a1 = {0,0,0,0}, a2 = {0,0,0,0};
            if (gi) {
                #pragma unroll
                for (int kk = 0; kk < 16; ++kk) {
                    half8 a = LDS_A(ldsY, kk);
                    a0 = mfma16(a, w0[kk], a0);
                    a1 = mfma16(a, w1[kk], a1);
                    a2 = mfma16(a, w2[kk], a2);
                }
                #pragma unroll
                for (int jj = 0; jj < 4; ++jj) {
                    int rr = (rb + jj) * 17 + cv;
                    ldsAcc[wid][0][rr] = a0[jj];
                    ldsAcc[wid][1][rr] = a1[jj];
                    ldsAcc[wid][2][rr] = a2[jj];
                }
            } else {
                #pragma unroll
                for (int kk = 0; kk < 16; ++kk) {
                    half8 a = LDS_A(ldsH, kk);
                    a0 = mfma16(a, w0[kk], a0);
                    a1 = mfma16(a, w1[kk], a1);
                    a2 = mfma16(a, w2[kk], a2);
                }
            }
            __syncthreads();
            if (!gi) {
                float hv[4];
                #pragma unroll
                for (int jj = 0; jj < 4; ++jj) {
                    int b = row0 + rb + jj;
                    int rr = (rb + jj) * 17 + cv;
                    float gr = ldsAcc[wid & 3][0][rr];
                    float gz = ldsAcc[wid & 3][1][rr];
                    float gn = ldsAcc[wid & 3][2][rr];
                    float r = sigf(gr + a0[jj] + bCr);
                    float z = sigf(gz + a1[jj] + bCz);
                    float n = tanhf(gn + bIn + r * (a2[jj] + bHn));
                    hv[jj] = (1.0f - z) * n + z * hold[jj];
                    hold[jj] = hv[jj];
                    if (u == Tlen - 1) a_st4(hT1 + (size_t)b * Hdim + hid, hv[jj]);
                }
                STORE_SEQ(r1rg + (size_t)(u & 3) * (16 * RUNITS), u + 1,
                          hv[0], hv[1], hv[2], hv[3]);
            }
        }
        if (!gi) sigS(fEnc1 + hs, 1);
    }

    // ================= LayerNorm =================
    if (poolA && g == 0 && wid == 0) {
        waitS<32>(fEnc0, 1);
        ln_rows(hT0, h0d[1] + rgbase, lng, lnb, row0, lane);
        if (lane < 16) {
            int b = row0 + lane;
            a_st4(ybuf + b, x[((size_t)b * Tlen + (Tlen - 1)) * 2 + 1]);
        }
        sigS(fLN + 0, 1);
    }
    if (!poolA && g == 4 && wid == 0) {
        waitS<32>(fEnc1, 1);
        ln_rows(hT1, h1d[1] + rgbase, lng, lnb, row0, lane);
        sigS(fLN + 1, 1);
    }

    // ---- decoder weights ----
    {
        const float* wsP = poolA ? dwhh0 : (gi ? dwih1 : dwhh1);
        const float* b0 = wsP + (size_t)hid * Hdim + kg * 8;
        #pragma unroll
        for (int kk = 0; kk < 16; ++kk) {
            w0[kk] = ld_cvt(b0 + kk * 32);
            w1[kk] = ld_cvt(b0 + (size_t)512 * Hdim + kk * 32);
            w2[kk] = ld_cvt(b0 + (size_t)1024 * Hdim + kk * 32);
        }
    }
    if (poolA) {
        cw_r0 = dwih0[hid]; cw_z0 = dwih0[512 + hid]; cw_n0 = dwih0[1024 + hid];
        bCr = dbih0[hid] + dbhh0[hid];
        bCz = dbih0[512 + hid] + dbhh0[512 + hid];
        bIn = dbih0[1024 + hid]; bHn = dbhh0[1024 + hid];
    } else if (!gi) {
        bCr = dbih1[hid] + dbhh1[hid];
        bCz = dbih1[512 + hid] + dbhh1[512 + hid];
        bIn = dbih1[1024 + hid]; bHn = dbhh1[1024 + hid];
    }
    float fw[8] = {0,0,0,0,0,0,0,0};
    float fb = 0.f;
    const bool is_fc = (!poolA) && (g == 4) && (wid == 7);
    if (is_fc) {
        #pragma unroll
        for (int e = 0; e < 8; ++e) fw[e] = fcw[lane * 8 + e];
        fb = fcb[0];
    }
    waitS<2>(fLN, 1);
    if (poolA) {
        #pragma unroll
        for (int jj = 0; jj < 4; ++jj)
            hold[jj] = a_ld4(hT0 + (size_t)(row0 + rb + jj) * Hdim + hid);
    } else if (!gi) {
        #pragma unroll
        for (int jj = 0; jj < 4; ++jj)
            hold[jj] = a_ld4(hT1 + (size_t)(row0 + rb + jj) * Hdim + hid);
    }

    // ================= decoder: 10 steps (r12-proven flag scheme) =================
    if (poolA) {
        for (int t = 0; t < OUTL; ++t) {
            waitS<32>(fD0, t);
            waitS<1>(fY, t);
            {
                const _Float16* s = h0d[(t + 1) & 1] + rgbase;
                u64 tv[4];
                #pragma unroll
                for (int u = 0; u < 4; ++u) tv[u] = a_ld8(s + (tid + u * 512) * 4);
                #pragma unroll
                for (int u = 0; u < 4; ++u) *(u64*)&ldsY[(tid + u * 512) * 4] = tv[u];
            }
            __syncthreads();
            float yvv[4];
            #pragma unroll
            for (int jj = 0; jj < 4; ++jj) yvv[jj] = a_ld4(ybuf + row0 + rb + jj);
            f32x4 a0 = {0,0,0,0}, a1 = {0,0,0,0}, a2 = {0,0,0,0};
            #pragma unroll
            for (int kk = 0; kk < 16; ++kk) {
                half8 a = LDS_A(ldsY, kk);
                a0 = mfma16(a, w0[kk], a0);
                a1 = mfma16(a, w1[kk], a1);
                a2 = mfma16(a, w2[kk], a2);
            }
            float hv[4];
            #pragma unroll
            for (int jj = 0; jj < 4; ++jj) {
                float yv = yvv[jj];
                float r = sigf(yv * cw_r0 + a0[jj] + bCr);
                float z = sigf(yv * cw_z0 + a1[jj] + bCz);
                float n = tanhf(yv * cw_n0 + bIn + r * (a2[jj] + bHn));
                hv[jj] = (1.0f - z) * n + z * hold[jj];
                hold[jj] = hv[jj];
            }
            STORE_TILE(h0d[t & 1], hv[0], hv[1], hv[2], hv[3]);
            sigS(fD0 + hs, t + 1);
        }
    } else {
        for (int t = 0; t < OUTL; ++t) {
            waitS<32>(fD1, t);
            {
                const _Float16* s = h1d[(t + 1) & 1] + rgbase;
                u64 tv[4];
                #pragma unroll
                for (int u = 0; u < 4; ++u) tv[u] = a_ld8(s + (tid + u * 512) * 4);
                #pragma unroll
                for (int u = 0; u < 4; ++u) *(u64*)&ldsH[(tid + u * 512) * 4] = tv[u];
            }
            __syncthreads();
            f32x4 a0 = {0,0,0,0}, a1 = {0,0,0,0}, a2 = {0,0,0,0};
            if (gi) {
                waitS<32>(fD0, t + 1);
                const _Float16* agb = h0d[t & 1] + rgbase;
                #pragma unroll
                for (int kk = 0; kk < 16; ++kk) {
                    const _Float16* pa = agb + (2 * kk + (kg >> 1)) * 256
                                       + cv * 16 + (kg & 1) * 8;
                    half8 q = h8(a_ld8(pa), a_ld8(pa + 4));
                    a0 = mfma16(q, w0[kk], a0);
                    a1 = mfma16(q, w1[kk], a1);
                    a2 = mfma16(q, w2[kk], a2);
                }
                #pragma unroll
                for (int jj = 0; jj < 4; ++jj) {
                    int rr = (rb + jj) * 17 + cv;
                    ldsAcc[wid][0][rr] = a0[jj];
                    ldsAcc[wid][1][rr] = a1[jj];
                    ldsAcc[wid][2][rr] = a2[jj];
                }
            } else {
                #pragma unroll
                for (int kk = 0; kk < 16; ++kk) {
                    half8 a = LDS_A(ldsH, kk);
                    a0 = mfma16(a, w0[kk], a0);
                    a1 = mfma16(a, w1[kk], a1);
                    a2 = mfma16(a, w2[kk], a2);
                }
            }
            __syncthreads();
            if (!gi) {
                float hv[4];
                #pragma unroll
                for (int jj = 0; jj < 4; ++jj) {
                    int rr = (rb + jj) * 17 + cv;
                    float gr = ldsAcc[wid & 3][0][rr];
                    float gz = ldsAcc[wid & 3][1][rr];
                    float gn = ldsAcc[wid & 3][2][rr];
                    float r = sigf(gr + a0[jj] + bCr);
                    float z = sigf(gz + a1[jj] + bCz);
                    float n = tanhf(gn + bIn + r * (a2[jj] + bHn));
                    hv[jj] = (1.0f - z) * n + z * hold[jj];
                    hold[jj] = hv[jj];
                }
                STORE_TILE(h1d[t & 1], hv[0], hv[1], hv[2], hv[3]);
                sigS(fD1 + hs, t + 1);
                if (is_fc) {
                    waitS<32>(fD1, t + 1);
                    const _Float16* hb = h1d[t & 1] + rgbase;
                    #pragma unroll 1
                    for (int r2 = 0; r2 < 16; ++r2) {
                        const _Float16* hp8 = hb + (lane >> 1) * 256 + r2 * 16 + (lane & 1) * 8;
                        half8 hv8 = h8(a_ld8(hp8), a_ld8(hp8 + 4));
                        float pa = 0.f;
                        #pragma unroll
                        for (int e = 0; e < 8; ++e) pa += (float)hv8[e] * fw[e];
                        #pragma unroll
                        for (int m = 1; m < 64; m <<= 1) pa += __shfl_xor(pa, m);
                        if (lane == 0) {
                            int b = row0 + r2;
                            float yv2 = pa + fb;
                            a_st4(ybuf + b, yv2);
                            out[(size_t)b * OUTL + t] = yv2;
                        }
                    }
                    sigS(fY, t + 1);
                }
            }
        }
    }
#undef STORE_SEQ
#undef STORE_TILE
#undef LDS_A
}

extern "C" void kernel_launch(void* const* d_in, const int* in_sizes, int n_in,
                              void* d_out, int out_size, void* d_ws, size_t ws_size,
                              hipStream_t stream)
{
    (void)in_sizes; (void)n_in; (void)out_size; (void)ws_size;
    hipMemsetAsync(d_ws, 0, ZBYTES, stream);
    gru_all<<<192, 512, 0, stream>>>(
        (const float*)d_in[0],
        (const float*)d_in[1],  (const float*)d_in[2],
        (const float*)d_in[3],  (const float*)d_in[4],
        (const float*)d_in[5],  (const float*)d_in[6],
        (const float*)d_in[7],  (const float*)d_in[8],
        (const float*)d_in[9],  (const float*)d_in[10],
        (const float*)d_in[11], (const float*)d_in[12],
        (const float*)d_in[13], (const float*)d_in[14],
        (const float*)d_in[15], (const float*)d_in[16],
        (const float*)d_in[17], (const float*)d_in[18],
        (const float*)d_in[19], (const float*)d_in[20],
        (float*)d_out, (char*)d_ws);
}

// Round 14
// 3574.006 us; speedup vs baseline: 9.0241x; 1.1758x over previous
//
#include <hip/hip_runtime.h>
#include <math.h>

// Seq2SeqGRU persistent kernel: r12 split-pool structure + r10 L2-amortized data.
// B=256, T=512, H=512, OUT=10. 192 WGs x 512 thr; rg=blockIdx&15, g=blockIdx>>4:
//   g<4: POOL A (layer0/dec0): 8 waves, slice hs=g*8+wid.
//   g>=4: POOL B (layer1/dec1): waves 0-3 gi, 4-7 gh; hs=(g-4)*4+(wid&3).
// All WGs of a rg land on XCD rg%8 (blockIdx%8 = rg%8) -> producer plain stores
// write-through the SHARED XCD L2 (update-on-hit); consumers: sc1 flag poll ->
// buffer_inv sc0 (L1-only) -> plain 16B loads: first reader fills L2 from MALL,
// the other 11 readers HIT L2. Kills r12/r13's 82K-sc1-requests/XCD/step
// bottleneck (~8.5us/step request-rate bound). Flags stay sc1 (r7-proven).

#define Hdim 512
#define Bsz  256
#define Tlen 512
#define OUTL 10

typedef _Float16 half8 __attribute__((ext_vector_type(8)));
typedef float    f32x4 __attribute__((ext_vector_type(4)));
typedef unsigned long long u64;

__device__ __forceinline__ f32x4 mfma16(half8 a, half8 b, f32x4 c) {
    return __builtin_amdgcn_mfma_f32_16x16x32_f16(a, b, c, 0, 0, 0);
}
__device__ __forceinline__ float sigf(float v) { return 1.0f / (1.0f + __expf(-v)); }

// ---- relaxed agent-scope (sc1) prims — flags only ----
__device__ __forceinline__ int a_ldi(const int* p) {
    return __hip_atomic_load(p, __ATOMIC_RELAXED, __HIP_MEMORY_SCOPE_AGENT); }
__device__ __forceinline__ void a_sti(int* p, int v) {
    __hip_atomic_store(p, v, __ATOMIC_RELAXED, __HIP_MEMORY_SCOPE_AGENT); }

// L1-only invalidate (r10-proven): drops stale L1 lines; L2 stays intact.
__device__ __forceinline__ void l1inv() {
    asm volatile("buffer_inv sc0" ::: "memory");
}

// signal: drain plain data stores (write-through accepted by L2), then sc1 flag.
__device__ __forceinline__ void sigS(int* slot, int val) {
    asm volatile("s_waitcnt vmcnt(0)" ::: "memory");
    if ((threadIdx.x & 63) == 0) a_sti(slot, val);
}
template <int NS>
__device__ __forceinline__ void waitS(int* base, int target) {
    if (target <= 0) return;
    int* p = base + ((threadIdx.x & 63) % NS);
    while (true) {
        int v = a_ldi(p);
        if (__all(v >= target)) break;
        __builtin_amdgcn_s_sleep(1);
    }
    asm volatile("" ::: "memory");
}

__device__ __forceinline__ half8 ld_cvt(const float* p) {
    float4 a = *(const float4*)p;
    float4 b = *(const float4*)(p + 4);
    half8 v;
    v[0]=(_Float16)a.x; v[1]=(_Float16)a.y; v[2]=(_Float16)a.z; v[3]=(_Float16)a.w;
    v[4]=(_Float16)b.x; v[5]=(_Float16)b.y; v[6]=(_Float16)b.z; v[7]=(_Float16)b.w;
    return v;
}

// LayerNorm of 16 rows (one wave), PLAIN loads/stores (caller: flags waited +
// l1inv done; sigS after drains). dst16rg = tile-major f16 copy at rg base.
__device__ void ln_rows(float* hT, _Float16* dst16rg, const float* gam, const float* bet,
                        int row0, int lane) {
    #pragma unroll 1
    for (int r = 0; r < 16; ++r) {
        float* pr_ = hT + (size_t)(row0 + r) * Hdim;
        float4 v0 = *(const float4*)(pr_ + lane * 8);
        float4 v1 = *(const float4*)(pr_ + lane * 8 + 4);
        float v[8] = {v0.x, v0.y, v0.z, v0.w, v1.x, v1.y, v1.z, v1.w};
        float s = 0.f, sq = 0.f;
        #pragma unroll
        for (int e = 0; e < 8; ++e) { s += v[e]; sq += v[e] * v[e]; }
        #pragma unroll
        for (int m = 1; m < 64; m <<= 1) { s += __shfl_xor(s, m); sq += __shfl_xor(sq, m); }
        float mean = s * (1.0f / Hdim);
        float rstd = rsqrtf(sq * (1.0f / Hdim) - mean * mean + 1e-5f);
        _Float16* d = dst16rg + (lane >> 1) * 256 + r * 16 + (lane & 1) * 8;
        #pragma unroll
        for (int e = 0; e < 8; ++e) {
            int k = lane * 8 + e;
            float o = (v[e] - mean) * rstd * gam[k] + bet[k];
            pr_[k] = o;
            d[e] = (_Float16)o;
        }
    }
}

// ws layout
#define OFF_FLAGS 0
#define SZ_FLAGS  (6 * 16 * 32 * 4)            // f0,f1,fD0,fD1,fLN,fY
#define H16B      262144                        // one f16 h buffer (256x512)
#define OFF_H0R   (OFF_FLAGS + SZ_FLAGS)        // ring-4
#define OFF_H1R   (OFF_H0R + 4 * H16B)          // ring-2
#define ZBYTES    (OFF_H1R + 2 * H16B)
#define OFF_H0D   ZBYTES
#define OFF_H1D   (OFF_H0D + 2 * H16B)
#define OFF_HT0   (OFF_H1D + 2 * H16B)
#define OFF_HT1   (OFF_HT0 + 524288)
#define OFF_YB    (OFF_HT1 + 524288)

__global__ __launch_bounds__(512, 1) void gru_all(
    const float* __restrict__ x,
    const float* __restrict__ ewih0, const float* __restrict__ ewhh0,
    const float* __restrict__ ebih0, const float* __restrict__ ebhh0,
    const float* __restrict__ ewih1, const float* __restrict__ ewhh1,
    const float* __restrict__ ebih1, const float* __restrict__ ebhh1,
    const float* __restrict__ lng,   const float* __restrict__ lnb,
    const float* __restrict__ dwih0, const float* __restrict__ dwhh0,
    const float* __restrict__ dbih0, const float* __restrict__ dbhh0,
    const float* __restrict__ dwih1, const float* __restrict__ dwhh1,
    const float* __restrict__ dbih1, const float* __restrict__ dbhh1,
    const float* __restrict__ fcw,   const float* __restrict__ fcb,
    float* __restrict__ out, char* __restrict__ ws)
{
    __shared__ _Float16 ldsY[8192];
    __shared__ _Float16 ldsH[8192];
    __shared__ float    ldsAcc[4][3][272];
    __shared__ _Float16 ldsOut[8][256];

    const int tid  = threadIdx.x;
    const int wid  = tid >> 6, lane = tid & 63;
    const int rg   = blockIdx.x & 15;
    const int g    = blockIdx.x >> 4;
    const bool poolA = (g < 4);
    const int cv   = lane & 15, kg = lane >> 4;
    const int row0 = rg * 16;
    const int rb   = kg * 4;
    const size_t rgbase = (size_t)rg * 32 * 256;

    int* flags = (int*)(ws + OFF_FLAGS);
    int* f0  = flags + (0 * 16 + rg) * 32;
    int* f1  = flags + (1 * 16 + rg) * 32;
    int* fD0 = flags + (2 * 16 + rg) * 32;
    int* fD1 = flags + (3 * 16 + rg) * 32;
    int* fLN = flags + (4 * 16 + rg) * 32;
    int* fY  = flags + (5 * 16 + rg) * 32;
    _Float16* h0r[4] = {(_Float16*)(ws+OFF_H0R), (_Float16*)(ws+OFF_H0R+H16B),
                        (_Float16*)(ws+OFF_H0R+2*H16B), (_Float16*)(ws+OFF_H0R+3*H16B)};
    _Float16* h1r[2] = {(_Float16*)(ws+OFF_H1R), (_Float16*)(ws+OFF_H1R+H16B)};
    _Float16* h0d[2] = {(_Float16*)(ws+OFF_H0D), (_Float16*)(ws+OFF_H0D+H16B)};
    _Float16* h1d[2] = {(_Float16*)(ws+OFF_H1D), (_Float16*)(ws+OFF_H1D+H16B)};
    float* hT0  = (float*)(ws + OFF_HT0);
    float* hT1  = (float*)(ws + OFF_HT1);
    float* ybuf = (float*)(ws + OFF_YB);

    const bool gi = (!poolA) && (wid < 4);
    const int  hs = poolA ? (g * 8 + wid) : ((g - 4) * 4 + (wid & 3));
    const int  hid = hs * 16 + cv;
    const int  ow = poolA ? wid : (wid & 3);

#define LDS_A(ARR, KK) \
    (*(const half8*)&(ARR)[(2 * (KK) + (kg >> 1)) * 256 + cv * 16 + (kg & 1) * 8])
    // PLAIN tile store (write-through -> XCD L2 update/forward); drained by sigS.
#define STORE_TILE(DST, HV0, HV1, HV2, HV3)                                      \
    do {                                                                         \
        ldsOut[ow][(rb + 0) * 16 + cv] = (_Float16)(HV0);                        \
        ldsOut[ow][(rb + 1) * 16 + cv] = (_Float16)(HV1);                        \
        ldsOut[ow][(rb + 2) * 16 + cv] = (_Float16)(HV2);                        \
        ldsOut[ow][(rb + 3) * 16 + cv] = (_Float16)(HV3);                        \
        u64 pk_ = *(const u64*)&ldsOut[ow][lane * 4];                            \
        *(u64*)((DST) + rgbase + (size_t)hs * 256 + lane * 4) = pk_;             \
    } while (0)
    // PLAIN 16KB stage (after l1inv): 2x half8 per thread, L2-served fan-out.
#define STAGE16(LDS, SRC)                                                        \
    do {                                                                         \
        const _Float16* s_ = (SRC);                                              \
        half8 v0_ = *(const half8*)(s_ + tid * 8);                               \
        half8 v1_ = *(const half8*)(s_ + (tid + 512) * 8);                       \
        *(half8*)&(LDS)[tid * 8] = v0_;                                          \
        *(half8*)&(LDS)[(tid + 512) * 8] = v1_;                                  \
    } while (0)

    // ---- encoder weights -> registers ----
    half8 w0[16], w1[16], w2[16];
    {
        const float* wsP = poolA ? ewhh0 : (gi ? ewih1 : ewhh1);
        const float* b0 = wsP + (size_t)hid * Hdim + kg * 8;
        #pragma unroll
        for (int kk = 0; kk < 16; ++kk) {
            w0[kk] = ld_cvt(b0 + kk * 32);
            w1[kk] = ld_cvt(b0 + (size_t)512 * Hdim + kk * 32);
            w2[kk] = ld_cvt(b0 + (size_t)1024 * Hdim + kk * 32);
        }
    }
    float cw_r0 = 0, cw_r1 = 0, cw_z0 = 0, cw_z1 = 0, cw_n0 = 0, cw_n1 = 0;
    float bCr = 0, bCz = 0, bIn = 0, bHn = 0;
    if (poolA) {
        cw_r0 = ewih0[hid * 2];          cw_r1 = ewih0[hid * 2 + 1];
        cw_z0 = ewih0[(512 + hid) * 2];  cw_z1 = ewih0[(512 + hid) * 2 + 1];
        cw_n0 = ewih0[(1024 + hid) * 2]; cw_n1 = ewih0[(1024 + hid) * 2 + 1];
        bCr = ebih0[hid] + ebhh0[hid];
        bCz = ebih0[512 + hid] + ebhh0[512 + hid];
        bIn = ebih0[1024 + hid]; bHn = ebhh0[1024 + hid];
    } else if (!gi) {
        bCr = ebih1[hid] + ebhh1[hid];
        bCz = ebih1[512 + hid] + ebhh1[512 + hid];
        bIn = ebih1[1024 + hid]; bHn = ebhh1[1024 + hid];
    }
    float hold[4] = {0.f, 0.f, 0.f, 0.f};

    // ================= encoder =================
    if (poolA) {
        for (int i = 0; i < Tlen; ++i) {
            float2 xv[4];
            #pragma unroll
            for (int jj = 0; jj < 4; ++jj)
                xv[jj] = *(const float2*)(x + ((size_t)(row0 + rb + jj) * Tlen + i) * 2);
            waitS<32>(f1, i - 3);            // ring-4 back-pressure on y0 slots
            waitS<32>(f0, i);                // h0[i-1] ready
            l1inv();
            STAGE16(ldsY, h0r[(i + 3) & 3] + rgbase);
            __syncthreads();
            f32x4 a0 = {0,0,0,0}, a1 = {0,0,0,0}, a2 = {0,0,0,0};
            #pragma unroll
            for (int kk = 0; kk < 16; ++kk) {
                half8 a = LDS_A(ldsY, kk);
                a0 = mfma16(a, w0[kk], a0);
                a1 = mfma16(a, w1[kk], a1);
                a2 = mfma16(a, w2[kk], a2);
            }
            float hv[4];
            #pragma unroll
            for (int jj = 0; jj < 4; ++jj) {
                int b = row0 + rb + jj;
                float x0 = xv[jj].x, x1 = xv[jj].y;
                float r = sigf(x0 * cw_r0 + x1 * cw_r1 + a0[jj] + bCr);
                float z = sigf(x0 * cw_z0 + x1 * cw_z1 + a1[jj] + bCz);
                float n = tanhf(x0 * cw_n0 + x1 * cw_n1 + bIn + r * (a2[jj] + bHn));
                hv[jj] = (1.0f - z) * n + z * hold[jj];
                hold[jj] = hv[jj];
                if (i == Tlen - 1) hT0[(size_t)b * Hdim + hid] = hv[jj];
            }
            STORE_TILE(h0r[i & 3], hv[0], hv[1], hv[2], hv[3]);
            sigS(f0 + hs, i + 1);
        }
    } else {
        for (int u = 0; u < Tlen; ++u) {
            waitS<32>(f1, u);                // h1[u-1] ready
            waitS<32>(f0, u + 1);            // y0[u] ready
            l1inv();
            STAGE16(ldsY, h0r[u & 3] + rgbase);
            STAGE16(ldsH, h1r[(u + 1) & 1] + rgbase);
            __syncthreads();
            f32x4 a0 = {0,0,0,0}, a1 = {0,0,0,0}, a2 = {0,0,0,0};
            if (gi) {
                #pragma unroll
                for (int kk = 0; kk < 16; ++kk) {
                    half8 a = LDS_A(ldsY, kk);
                    a0 = mfma16(a, w0[kk], a0);
                    a1 = mfma16(a, w1[kk], a1);
                    a2 = mfma16(a, w2[kk], a2);
                }
                #pragma unroll
                for (int jj = 0; jj < 4; ++jj) {
                    int rr = (rb + jj) * 17 + cv;
                    ldsAcc[wid][0][rr] = a0[jj];
                    ldsAcc[wid][1][rr] = a1[jj];
                    ldsAcc[wid][2][rr] = a2[jj];
                }
            } else {
                #pragma unroll
                for (int kk = 0; kk < 16; ++kk) {
                    half8 a = LDS_A(ldsH, kk);
                    a0 = mfma16(a, w0[kk], a0);
                    a1 = mfma16(a, w1[kk], a1);
                    a2 = mfma16(a, w2[kk], a2);
                }
            }
            __syncthreads();
            if (!gi) {
                float hv[4];
                #pragma unroll
                for (int jj = 0; jj < 4; ++jj) {
                    int b = row0 + rb + jj;
                    int rr = (rb + jj) * 17 + cv;
                    float gr = ldsAcc[wid & 3][0][rr];
                    float gz = ldsAcc[wid & 3][1][rr];
                    float gn = ldsAcc[wid & 3][2][rr];
                    float r = sigf(gr + a0[jj] + bCr);
                    float z = sigf(gz + a1[jj] + bCz);
                    float n = tanhf(gn + bIn + r * (a2[jj] + bHn));
                    hv[jj] = (1.0f - z) * n + z * hold[jj];
                    hold[jj] = hv[jj];
                    if (u == Tlen - 1) hT1[(size_t)b * Hdim + hid] = hv[jj];
                }
                STORE_TILE(h1r[u & 1], hv[0], hv[1], hv[2], hv[3]);
                sigS(f1 + hs, u + 1);
            }
        }
    }

    // ================= LayerNorm =================
    if (poolA && g == 0 && wid == 0) {
        waitS<32>(f0, Tlen);                 // own-pool drains done (hT0 visible)
        l1inv();
        ln_rows(hT0, h0d[1] + rgbase, lng, lnb, row0, lane);
        if (lane < 16) {
            int b = row0 + lane;
            ybuf[b] = x[((size_t)b * Tlen + (Tlen - 1)) * 2 + 1];
        }
        sigS(fLN + 0, 1);
    }
    if (!poolA && g == 4 && wid == 0) {
        waitS<32>(f1, Tlen);
        l1inv();
        ln_rows(hT1, h1d[1] + rgbase, lng, lnb, row0, lane);
        sigS(fLN + 1, 1);
    }

    // ---- decoder weights ----
    {
        const float* wsP = poolA ? dwhh0 : (gi ? dwih1 : dwhh1);
        const float* b0 = wsP + (size_t)hid * Hdim + kg * 8;
        #pragma unroll
        for (int kk = 0; kk < 16; ++kk) {
            w0[kk] = ld_cvt(b0 + kk * 32);
            w1[kk] = ld_cvt(b0 + (size_t)512 * Hdim + kk * 32);
            w2[kk] = ld_cvt(b0 + (size_t)1024 * Hdim + kk * 32);
        }
    }
    if (poolA) {
        cw_r0 = dwih0[hid]; cw_z0 = dwih0[512 + hid]; cw_n0 = dwih0[1024 + hid];
        bCr = dbih0[hid] + dbhh0[hid];
        bCz = dbih0[512 + hid] + dbhh0[512 + hid];
        bIn = dbih0[1024 + hid]; bHn = dbhh0[1024 + hid];
    } else if (!gi) {
        bCr = dbih1[hid] + dbhh1[hid];
        bCz = dbih1[512 + hid] + dbhh1[512 + hid];
        bIn = dbih1[1024 + hid]; bHn = dbhh1[1024 + hid];
    }
    float fw[8] = {0,0,0,0,0,0,0,0};
    float fb = 0.f;
    const bool is_fc = (!poolA) && (g == 4) && (wid == 7);
    if (is_fc) {
        #pragma unroll
        for (int e = 0; e < 8; ++e) fw[e] = fcw[lane * 8 + e];
        fb = fcb[0];
    }
    waitS<2>(fLN, 1);
    l1inv();
    if (poolA) {
        #pragma unroll
        for (int jj = 0; jj < 4; ++jj)
            hold[jj] = hT0[(size_t)(row0 + rb + jj) * Hdim + hid];
    } else if (!gi) {
        #pragma unroll
        for (int jj = 0; jj < 4; ++jj)
            hold[jj] = hT1[(size_t)(row0 + rb + jj) * Hdim + hid];
    }

    // ================= decoder: 10 steps =================
    if (poolA) {
        for (int t = 0; t < OUTL; ++t) {
            waitS<32>(fD0, t);
            waitS<1>(fY, t);
            l1inv();
            STAGE16(ldsY, h0d[(t + 1) & 1] + rgbase);
            __syncthreads();
            float yvv[4];
            #pragma unroll
            for (int jj = 0; jj < 4; ++jj) yvv[jj] = ybuf[row0 + rb + jj];
            f32x4 a0 = {0,0,0,0}, a1 = {0,0,0,0}, a2 = {0,0,0,0};
            #pragma unroll
            for (int kk = 0; kk < 16; ++kk) {
                half8 a = LDS_A(ldsY, kk);
                a0 = mfma16(a, w0[kk], a0);
                a1 = mfma16(a, w1[kk], a1);
                a2 = mfma16(a, w2[kk], a2);
            }
            float hv[4];
            #pragma unroll
            for (int jj = 0; jj < 4; ++jj) {
                float yv = yvv[jj];
                float r = sigf(yv * cw_r0 + a0[jj] + bCr);
                float z = sigf(yv * cw_z0 + a1[jj] + bCz);
                float n = tanhf(yv * cw_n0 + bIn + r * (a2[jj] + bHn));
                hv[jj] = (1.0f - z) * n + z * hold[jj];
                hold[jj] = hv[jj];
            }
            STORE_TILE(h0d[t & 1], hv[0], hv[1], hv[2], hv[3]);
            sigS(fD0 + hs, t + 1);
        }
    } else {
        for (int t = 0; t < OUTL; ++t) {
            waitS<32>(fD1, t);
            l1inv();
            STAGE16(ldsH, h1d[(t + 1) & 1] + rgbase);
            __syncthreads();
            f32x4 a0 = {0,0,0,0}, a1 = {0,0,0,0}, a2 = {0,0,0,0};
            if (gi) {
                waitS<32>(fD0, t + 1);       // fresh h0dec[t]
                l1inv();
                const _Float16* agb = h0d[t & 1] + rgbase;
                #pragma unroll
                for (int kk = 0; kk < 16; ++kk) {
                    const _Float16* pa = agb + (2 * kk + (kg >> 1)) * 256
                                       + cv * 16 + (kg & 1) * 8;
                    half8 q = *(const half8*)pa;
                    a0 = mfma16(q, w0[kk], a0);
                    a1 = mfma16(q, w1[kk], a1);
                    a2 = mfma16(q, w2[kk], a2);
                }
                #pragma unroll
                for (int jj = 0; jj < 4; ++jj) {
                    int rr = (rb + jj) * 17 + cv;
                    ldsAcc[wid][0][rr] = a0[jj];
                    ldsAcc[wid][1][rr] = a1[jj];
                    ldsAcc[wid][2][rr] = a2[jj];
                }
            } else {
                #pragma unroll
                for (int kk = 0; kk < 16; ++kk) {
                    half8 a = LDS_A(ldsH, kk);
                    a0 = mfma16(a, w0[kk], a0);
                    a1 = mfma16(a, w1[kk], a1);
                    a2 = mfma16(a, w2[kk], a2);
                }
            }
            __syncthreads();
            if (!gi) {
                float hv[4];
                #pragma unroll
                for (int jj = 0; jj < 4; ++jj) {
                    int rr = (rb + jj) * 17 + cv;
                    float gr = ldsAcc[wid & 3][0][rr];
                    float gz = ldsAcc[wid & 3][1][rr];
                    float gn = ldsAcc[wid & 3][2][rr];
                    float r = sigf(gr + a0[jj] + bCr);
                    float z = sigf(gz + a1[jj] + bCz);
                    float n = tanhf(gn + bIn + r * (a2[jj] + bHn));
                    hv[jj] = (1.0f - z) * n + z * hold[jj];
                    hold[jj] = hv[jj];
                }
                STORE_TILE(h1d[t & 1], hv[0], hv[1], hv[2], hv[3]);
                sigS(fD1 + hs, t + 1);
                if (is_fc) {
                    waitS<32>(fD1, t + 1);
                    l1inv();
                    const _Float16* hb = h1d[t & 1] + rgbase;
                    #pragma unroll 1
                    for (int r2 = 0; r2 < 16; ++r2) {
                        const _Float16* hp8 = hb + (lane >> 1) * 256 + r2 * 16 + (lane & 1) * 8;
                        half8 hv8 = *(const half8*)hp8;
                        float pa = 0.f;
                        #pragma unroll
                        for (int e = 0; e < 8; ++e) pa += (float)hv8[e] * fw[e];
                        #pragma unroll
                        for (int m = 1; m < 64; m <<= 1) pa += __shfl_xor(pa, m);
                        if (lane == 0) {
                            int b = row0 + r2;
                            float yv2 = pa + fb;
                            ybuf[b] = yv2;
                            out[(size_t)b * OUTL + t] = yv2;
                        }
                    }
                    sigS(fY, t + 1);
                }
            }
        }
    }
#undef STORE_TILE
#undef STAGE16
#undef LDS_A
}

extern "C" void kernel_launch(void* const* d_in, const int* in_sizes, int n_in,
                              void* d_out, int out_size, void* d_ws, size_t ws_size,
                              hipStream_t stream)
{
    (void)in_sizes; (void)n_in; (void)out_size; (void)ws_size;
    hipMemsetAsync(d_ws, 0, ZBYTES, stream);
    gru_all<<<192, 512, 0, stream>>>(
        (const float*)d_in[0],
        (const float*)d_in[1],  (const float*)d_in[2],
        (const float*)d_in[3],  (const float*)d_in[4],
        (const float*)d_in[5],  (const float*)d_in[6],
        (const float*)d_in[7],  (const float*)d_in[8],
        (const float*)d_in[9],  (const float*)d_in[10],
        (const float*)d_in[11], (const float*)d_in[12],
        (const float*)d_in[13], (const float*)d_in[14],
        (const float*)d_in[15], (const float*)d_in[16],
        (const float*)d_in[17], (const float*)d_in[18],
        (const float*)d_in[19], (const float*)d_in[20],
        (float*)d_out, (char*)d_ws);
}